// Round 10
// baseline (198.832 us; speedup 1.0000x reference)
//
#include <hip/hip_runtime.h>
#include <math.h>

#define D_MODEL 1024
#define NHEADS  16
#define NKV     4
#define HDIM    64
#define KVDIM   256
#define BB      2
#define NN      2048
#define MROWS   (BB*NN)        // 4096
#define QKVN    1536           // 1024 + 256 + 256
#define NTASK   (MROWS*NHEADS) // 65536
#define NSPLIT  2
#define KVBLK   128
#define NTILE   ((NN/NSPLIT)/KVBLK)   // 8

typedef unsigned short ushort_t;
typedef unsigned int uint_t;
typedef float    f32x4 __attribute__((ext_vector_type(4)));
typedef _Float16 h16x8 __attribute__((ext_vector_type(8)));
typedef _Float16 h16x4 __attribute__((ext_vector_type(4)));
typedef __fp16   fp16x2 __attribute__((ext_vector_type(2)));

#define MFMAH(A,B,C)  __builtin_amdgcn_mfma_f32_16x16x32_f16((A),(B),(C),0,0,0)
// NOTE spelling: carried-forward GCN-era intrinsic has NO underscore before f16
#define MFMA16(A,B,C) __builtin_amdgcn_mfma_f32_16x16x16f16((A),(B),(C),0,0,0)
// raw v_exp_f32 (1 instr) -- libm exp2f carries a ~6-instr denormal fixup
#define EXP2(x) __builtin_amdgcn_exp2f(x)

// async global->LDS, 16B per lane; LDS dest = wave-uniform base + lane*16
#define GLDS(gp, lp) __builtin_amdgcn_global_load_lds( \
    (const __attribute__((address_space(1))) void*)(gp), \
    (__attribute__((address_space(3))) void*)(lp), 16, 0, 0)

__device__ __forceinline__ ushort_t f2h(float f) {
    _Float16 h = (_Float16)f;
    return *(ushort_t*)&h;
}
__device__ __forceinline__ float h2f(ushort_t u) {
    return (float)(*(const _Float16*)&u);
}
// two fp32 -> packed f16x2, single v_cvt_pkrtz_f16_f32
__device__ __forceinline__ uint_t pk2h(float a, float b) {
    fp16x2 v = __builtin_amdgcn_cvt_pkrtz(a, b);
    return *(uint_t*)&v;
}

// ---------------------------------------------------------------------------
// Fused prep: cast x->f16 (blocks [0,4096)) + 4 weight transpose-casts
// (blocks [4096,6656)). One dispatch instead of five.
// ---------------------------------------------------------------------------
__global__ __launch_bounds__(256)
void prep_kernel(const float* __restrict__ x, const float* __restrict__ Wq,
                 const float* __restrict__ Wk, const float* __restrict__ Wv,
                 const float* __restrict__ Wo, ushort_t* __restrict__ xb,
                 ushort_t* __restrict__ WqkvT, ushort_t* __restrict__ WoT)
{
    __shared__ float T[32][33];
    int blk = blockIdx.x;
    if (blk < 4096) {                      // cast: 4096*256*4 = 4M elements
        const int i = blk * 256 + threadIdx.x;
        float4 v = ((const float4*)x)[i];
        uint2 o;
        o.x = pk2h(v.x, v.y);
        o.y = pk2h(v.z, v.w);
        ((uint2*)xb)[i] = o;
        return;
    }
    blk -= 4096;
    const float* src; ushort_t* dst; int N, bx, by;
    if (blk < 1024)      { src = Wq; dst = WqkvT;                            N = D_MODEL; bx = blk & 31; by = blk >> 5; }
    else if (blk < 1280) { blk -= 1024; src = Wk; dst = WqkvT + (size_t)1024 * D_MODEL; N = KVDIM; bx = blk & 7; by = blk >> 3; }
    else if (blk < 1536) { blk -= 1280; src = Wv; dst = WqkvT + (size_t)1280 * D_MODEL; N = KVDIM; bx = blk & 7; by = blk >> 3; }
    else                 { blk -= 1536; src = Wo; dst = WoT;                 N = D_MODEL; bx = blk & 31; by = blk >> 5; }
    const int tx = threadIdx.x & 31, ty = threadIdx.x >> 5;
    const int n0 = bx * 32, k0 = by * 32;
#pragma unroll
    for (int i = 0; i < 4; i++)
        T[ty + i * 8][tx] = src[(size_t)(k0 + ty + i * 8) * N + n0 + tx];
    __syncthreads();
#pragma unroll
    for (int i = 0; i < 4; i++)
        dst[(size_t)(n0 + ty + i * 8) * D_MODEL + k0 + tx] = f2h(T[tx][ty + i * 8]);
}

// ---------------------------------------------------------------------------
// Fused K-RoPE + V transpose (Q-rope moved INTO attn). One dispatch.
// Blocks [0, NKBLK): K rope; blocks [NKBLK, +1024): vtrans.
// ---------------------------------------------------------------------------
#define NKW (MROWS*NKV*32)      //   524,288
#define NKBLK (NKW / 256)       //   2048
__global__ __launch_bounds__(256)
void ropevt_kernel(const ushort_t* __restrict__ QKVh, const float* __restrict__ Cos,
                   const float* __restrict__ Sin, ushort_t* __restrict__ Kb,
                   ushort_t* __restrict__ Vt)
{
    __shared__ ushort_t T[32][34];
    if (blockIdx.x >= NKBLK) {
        const int blk2 = blockIdx.x - NKBLK;
        const int bx = blk2 & 63, by = (blk2 >> 6) & 7, b = blk2 >> 9;
        const int tx = threadIdx.x & 31, ty = threadIdx.x >> 5;
        const int n0 = bx * 32, d0 = by * 32;
#pragma unroll
        for (int i = 0; i < 4; i++)
            T[ty + i * 8][tx] =
                QKVh[(size_t)(b * NN + n0 + ty + i * 8) * QKVN + 1280 + d0 + tx];
        __syncthreads();
#pragma unroll
        for (int i = 0; i < 4; i++)
            Vt[(size_t)(b * 256 + d0 + ty + i * 8) * NN + n0 + tx] = T[tx][ty + i * 8];
        return;
    }
    const int i2 = blockIdx.x * 256 + threadIdx.x;
    const int row = i2 >> 7, rem = i2 & 127;
    const int h = rem >> 5, j = rem & 31;
    const int b = row >> 11, n = row & (NN - 1);
    const uint_t pr = *(const uint_t*)&QKVh[(size_t)row * QKVN + 1024 + h * 64 + 2 * j];
    const float e = h2f((ushort_t)pr), o = h2f((ushort_t)(pr >> 16));
    const float c = Cos[n * 32 + j], s = Sin[n * 32 + j];
    ushort_t* dst = Kb + ((size_t)(b * 4 + h) * NN + n) * 64;
    dst[j]      = f2h(e * c - o * s);
    dst[j + 32] = f2h(e * s + o * c);
}

// ---------------------------------------------------------------------------
// f16 MFMA GEMM for QKV (f16 out), 128x64 tile (round-8 proven config),
// GLDS + XOR swizzle + double-buffered LDS, one barrier/iter.
// ---------------------------------------------------------------------------
__global__ __launch_bounds__(256)
void gemm_qkv(const ushort_t* __restrict__ A, const ushort_t* __restrict__ Bt,
              ushort_t* __restrict__ C, int M, int N, int K)
{
    __shared__ ushort_t As[2][128 * 32];
    __shared__ ushort_t Bs[2][64 * 32];

    const int tid  = threadIdx.x;
    const int wave = tid >> 6, lane = tid & 63;
    const int quad = lane >> 4, l16 = lane & 15;
    const int rowBase = blockIdx.y * 128, colBase = blockIdx.x * 64;
    const int wm = (wave >> 1) * 64, wn = (wave & 1) * 32;

    f32x4 acc[4][2];
    const f32x4 zz = {0.f, 0.f, 0.f, 0.f};
#pragma unroll
    for (int i = 0; i < 4; i++)
#pragma unroll
        for (int j = 0; j < 2; j++) acc[i][j] = zz;

    const int sr = wave * 32 + (lane >> 2);
    const int sc = ((lane & 3) ^ ((lane >> 3) & 3)) * 8;
    const ushort_t* Ag0 = A + (size_t)(rowBase + sr) * K + sc;
    const ushort_t* Ag1 = A + (size_t)(rowBase + sr + 16) * K + sc;
    const int segA0 = (wave * 2 + 0) * 512, segA1 = (wave * 2 + 1) * 512;
    const int br = wave * 16 + (lane >> 2);
    const ushort_t* Bg0 = Bt + (size_t)(colBase + br) * K + sc;
    const int segB = wave * 512;

    const int fcol = (quad ^ ((l16 >> 1) & 3)) * 8;

    GLDS(Ag0, &As[0][segA0]);
    GLDS(Ag1, &As[0][segA1]);
    GLDS(Bg0, &Bs[0][segB]);

    for (int k0 = 0; k0 < K; k0 += 32) {
        const int cur = (k0 >> 5) & 1, nxt = cur ^ 1;
        __syncthreads();
        if (k0 + 32 < K) {
            GLDS(Ag0 + k0 + 32, &As[nxt][segA0]);
            GLDS(Ag1 + k0 + 32, &As[nxt][segA1]);
            GLDS(Bg0 + k0 + 32, &Bs[nxt][segB]);
        }

        h16x8 af[4], bf[2];
#pragma unroll
        for (int mt = 0; mt < 4; mt++)
            af[mt] = *(const h16x8*)&As[cur][(wm + mt * 16 + l16) * 32 + fcol];
#pragma unroll
        for (int nt = 0; nt < 2; nt++)
            bf[nt] = *(const h16x8*)&Bs[cur][(wn + nt * 16 + l16) * 32 + fcol];
#pragma unroll
        for (int mt = 0; mt < 4; mt++)
#pragma unroll
            for (int nt = 0; nt < 2; nt++)
                acc[mt][nt] = MFMAH(af[mt], bf[nt], acc[mt][nt]);
    }

#pragma unroll
    for (int mt = 0; mt < 4; mt++)
#pragma unroll
        for (int nt = 0; nt < 2; nt++) {
            const int row = rowBase + wm + mt * 16 + quad * 4;
            const int col = colBase + wn + nt * 16 + l16;
#pragma unroll
            for (int r = 0; r < 4; r++)
                C[(size_t)(row + r) * N + col] = f2h(acc[mt][nt][r]);
        }
}

// ---------------------------------------------------------------------------
// MFMA flash attention. Round-22: round-20 structure + Q-RoPE fused into
// the Q fragment load. qf[mt][0] holds dims j=quad*8+i, qf[mt][1] holds
// j+32 -- exactly the RoPE output pair from input cols (2j, 2j+1) of the
// pre-rope QKVh row. One-time ~64 VALU ops/thread, amortized over 8 tiles;
// deletes Qbuf (16MB W + 32MB R) and 80% of the rope kernel.
// Keeps: in-register K=16 PV, raw v_exp, KVBLK=128, MFMA denominator.
// ---------------------------------------------------------------------------
__global__ __launch_bounds__(256)
void attn_mfma(const ushort_t* __restrict__ QKVh, const float* __restrict__ Cos,
               const float* __restrict__ Sin, const ushort_t* __restrict__ Kb,
               const ushort_t* __restrict__ Vt, ushort_t* __restrict__ Pnum,
               float* __restrict__ Pl)
{
    const int qt = blockIdx.x, h = blockIdx.y;
    const int b = blockIdx.z >> 1, chunk = blockIdx.z & 1;
    const int kvh = h >> 2;
    const int tid = threadIdx.x;
    const int wave = tid >> 6, lane = tid & 63;
    const int quad = lane >> 4, l16 = lane & 15;

    __shared__ ushort_t Ks[128][72];
    __shared__ ushort_t Vs[64][136];

    const int row0 = qt * 256 + wave * 64;
    const float SC = 0.125f * 1.44269504f;

    h16x8 qf[4][2];
#pragma unroll
    for (int mt = 0; mt < 4; mt++) {
        const int n = row0 + mt * 16 + l16;
        // pre-rope Q row: cols h*64 + [2j, 2j+1] for j = quad*8 + i
        const uint_t* pr =
            (const uint_t*)(QKVh + (size_t)(b * NN + n) * QKVN + h * 64) + quad * 8;
        uint4 pa = *(const uint4*)pr;
        uint4 pc = *(const uint4*)(pr + 4);
        const uint_t pk[8] = {pa.x, pa.y, pa.z, pa.w, pc.x, pc.y, pc.z, pc.w};
        const float4 c0 = *(const float4*)&Cos[(size_t)n * 32 + quad * 8];
        const float4 c1 = *(const float4*)&Cos[(size_t)n * 32 + quad * 8 + 4];
        const float4 s0 = *(const float4*)&Sin[(size_t)n * 32 + quad * 8];
        const float4 s1 = *(const float4*)&Sin[(size_t)n * 32 + quad * 8 + 4];
        const float cc[8] = {c0.x, c0.y, c0.z, c0.w, c1.x, c1.y, c1.z, c1.w};
        const float ss[8] = {s0.x, s0.y, s0.z, s0.w, s1.x, s1.y, s1.z, s1.w};
#pragma unroll
        for (int i = 0; i < 8; i++) {
            const float e = h2f((ushort_t)pk[i]);
            const float o = h2f((ushort_t)(pk[i] >> 16));
            qf[mt][0][i] = (_Float16)((e * cc[i] - o * ss[i]) * SC);
            qf[mt][1][i] = (_Float16)((e * ss[i] + o * cc[i]) * SC);
        }
    }

    h16x4 ones;
#pragma unroll
    for (int i = 0; i < 4; i++) ones[i] = (_Float16)1.0f;

    const ushort_t* kbase = Kb + (size_t)(b * 4 + kvh) * NN * 64;
    const ushort_t* vbase = Vt + (size_t)(b * 256 + kvh * 64) * NN;
    const int key_lo = chunk * (NN / NSPLIT);          // 1024-key chunk
    const int rot = (qt + ((h & 3) << 2)) & (NTILE - 1);

    const int srow = tid >> 2, sseg = (tid & 3) * 8;
    const ushort_t* kp_lane = kbase + (size_t)srow * 64 + sseg;   // + key*64
    const ushort_t* vp_lane = vbase + (size_t)srow * NN + sseg;   // + key

    const f32x4 zz = {0.f, 0.f, 0.f, 0.f};
    f32x4 o[4][4];
#pragma unroll
    for (int mt = 0; mt < 4; mt++)
#pragma unroll
        for (int dt = 0; dt < 4; dt++) o[mt][dt] = zz;
    f32x4 lsum[4];
#pragma unroll
    for (int mt = 0; mt < 4; mt++) lsum[mt] = zz;

    const int key0 = key_lo + rot * KVBLK;
    uint4 kreg0 = *(const uint4*)(kp_lane + (size_t)key0 * 64);
    uint4 kreg1 = *(const uint4*)(kp_lane + (size_t)key0 * 64 + 32);
    uint4 kreg2 = *(const uint4*)(kp_lane + (size_t)(key0 + 64) * 64);
    uint4 kreg3 = *(const uint4*)(kp_lane + (size_t)(key0 + 64) * 64 + 32);
    uint4 vreg0 = *(const uint4*)(vp_lane + key0);
    uint4 vreg1 = *(const uint4*)(vp_lane + key0 + 32);
    uint4 vreg2 = *(const uint4*)(vp_lane + key0 + 64);
    uint4 vreg3 = *(const uint4*)(vp_lane + key0 + 96);

    for (int t = 0; t < NTILE; t++) {
        __syncthreads();
        *(uint4*)&Ks[srow][sseg]           = kreg0;
        *(uint4*)&Ks[srow][sseg + 32]      = kreg1;
        *(uint4*)&Ks[srow + 64][sseg]      = kreg2;
        *(uint4*)&Ks[srow + 64][sseg + 32] = kreg3;
        *(uint4*)&Vs[srow][sseg]           = vreg0;
        *(uint4*)&Vs[srow][sseg + 32]      = vreg1;
        *(uint4*)&Vs[srow][sseg + 64]      = vreg2;
        *(uint4*)&Vs[srow][sseg + 96]      = vreg3;
        __syncthreads();

        if (t < NTILE - 1) {
            const int kn = key_lo + ((rot + t + 1) & (NTILE - 1)) * KVBLK;
            kreg0 = *(const uint4*)(kp_lane + (size_t)kn * 64);
            kreg1 = *(const uint4*)(kp_lane + (size_t)kn * 64 + 32);
            kreg2 = *(const uint4*)(kp_lane + (size_t)(kn + 64) * 64);
            kreg3 = *(const uint4*)(kp_lane + (size_t)(kn + 64) * 64 + 32);
            vreg0 = *(const uint4*)(vp_lane + kn);
            vreg1 = *(const uint4*)(vp_lane + kn + 32);
            vreg2 = *(const uint4*)(vp_lane + kn + 64);
            vreg3 = *(const uint4*)(vp_lane + kn + 96);
        }

        // ---- fused per-kt: S^T = K Q^T -> exp2 -> pack -> PV (K=16, P in regs)
#pragma unroll
        for (int kt = 0; kt < 8; kt++) {
            h16x8 kf0 = *(const h16x8*)&Ks[kt * 16 + l16][quad * 8];
            h16x8 kf1 = *(const h16x8*)&Ks[kt * 16 + l16][32 + quad * 8];
            // V fragments for this kt: A-layout (K=16) = Vt[d][kt*16+quad*4+i]
            h16x4 va[4];
#pragma unroll
            for (int dt = 0; dt < 4; dt++)
                va[dt] = *(const h16x4*)&Vs[dt * 16 + l16][kt * 16 + quad * 4];

            uint2 pb[4];
#pragma unroll
            for (int mt = 0; mt < 4; mt++) {
                f32x4 st = MFMAH(kf0, qf[mt][0], zz);
                st = MFMAH(kf1, qf[mt][1], st);
                pb[mt].x = pk2h(EXP2(st[0]), EXP2(st[1]));
                pb[mt].y = pk2h(EXP2(st[2]), EXP2(st[3]));
            }
#pragma unroll
            for (int mt = 0; mt < 4; mt++) {
                const h16x4 pbv = *(const h16x4*)&pb[mt];
#pragma unroll
                for (int dt = 0; dt < 4; dt++)
                    o[mt][dt] = MFMA16(va[dt], pbv, o[mt][dt]);
                lsum[mt] = MFMA16(ones, pbv, lsum[mt]);
            }
        }
    }

    const size_t task0 = (size_t)(b * 16 + h) * NN + row0;
    ushort_t* np = Pnum + ((size_t)chunk * NTASK + task0) * 64;
#pragma unroll
    for (int mt = 0; mt < 4; mt++) {
        const float lt = lsum[mt][0];    // denom for q=l16 (rows identical)
        const float inv = 1.0f / lt;
#pragma unroll
        for (int dt = 0; dt < 4; dt++) {
            f32x4 v = o[mt][dt];
            uint2 pk;
            pk.x = pk2h(v[0] * inv, v[1] * inv);
            pk.y = pk2h(v[2] * inv, v[3] * inv);
            *(uint2*)&np[(size_t)(mt * 16 + l16) * 64 + dt * 16 + quad * 4] = pk;
        }
        if (quad == 0)
            Pl[(size_t)chunk * NTASK + task0 + mt * 16 + l16] = lt;
    }
}

// ---------------------------------------------------------------------------
// Wo GEMM with FUSED split-K combine (round-8 proven 128x64 config):
// A combine during staging (stride-40 LDS, 2 barriers/iter); B via GLDS +
// XOR swizzle, double-buffered. fp32 out.
// ---------------------------------------------------------------------------
__global__ __launch_bounds__(256)
void gemm_wo(const ushort_t* __restrict__ Pnum, const float* __restrict__ Pl,
             const ushort_t* __restrict__ WoT, float* __restrict__ C)
{
    __shared__ ushort_t As[2][128 * 40];   // padded rows: conflict-free b128
    __shared__ ushort_t Bs[2][64 * 32];

    const int tid  = threadIdx.x;
    const int wave = tid >> 6, lane = tid & 63;
    const int quad = lane >> 4, l16 = lane & 15;
    const int rowBase = blockIdx.y * 128, colBase = blockIdx.x * 64;
    const int wm = (wave >> 1) * 64, wn = (wave & 1) * 32;

    f32x4 acc[4][2];
    const f32x4 zz = {0.f, 0.f, 0.f, 0.f};
#pragma unroll
    for (int i = 0; i < 4; i++)
#pragma unroll
        for (int j = 0; j < 2; j++) acc[i][j] = zz;

    // A combine-staging: lane handles rows r0, r0+64; 8 cols at c8
    const int r0 = tid >> 2;             // 0..63
    const int c8 = (tid & 3) * 8;
    const int bB = rowBase >> 11;        // batch (scalar: 128 | 2048)
    const int n0 = (rowBase & (NN - 1)) + r0;

    // B staging (GLDS + swizzle)
    const int br = wave * 16 + (lane >> 2);
    const int sc = ((lane & 3) ^ ((lane >> 3) & 3)) * 8;
    const ushort_t* Bg0 = WoT + (size_t)(colBase + br) * D_MODEL + sc;
    const int segB = wave * 512;
    const int fcol = (quad ^ ((l16 >> 1) & 3)) * 8;

    uint4 a0c0, a0c1, a1c0, a1c1;
    float l00, l01, l10, l11;
    // prefetch A inputs for K-slice k0
#define PREFA(k0) { \
        const int h_ = (k0) >> 6; \
        const int d_ = ((k0) & 63) + c8; \
        const size_t t0_ = ((size_t)(bB * 16 + h_) << 11) + n0; \
        const size_t t1_ = t0_ + 64; \
        a0c0 = *(const uint4*)&Pnum[t0_ * 64 + d_]; \
        a0c1 = *(const uint4*)&Pnum[((size_t)NTASK + t0_) * 64 + d_]; \
        a1c0 = *(const uint4*)&Pnum[t1_ * 64 + d_]; \
        a1c1 = *(const uint4*)&Pnum[((size_t)NTASK + t1_) * 64 + d_]; \
        l00 = Pl[t0_]; l01 = Pl[NTASK + t0_]; \
        l10 = Pl[t1_]; l11 = Pl[NTASK + t1_]; \
    }

    PREFA(0);
    GLDS(Bg0, &Bs[0][segB]);

    for (int k0 = 0; k0 < D_MODEL; k0 += 32) {
        const int cur = (k0 >> 5) & 1, nxt = cur ^ 1;
        __syncthreads();     // prev-iter frag reads done; Bs[cur] GLDS drained

        // combine + stage A (two rows)
        {
            const float i0 = 1.f / (l00 + l01), w00 = l00 * i0, w01 = l01 * i0;
            const float i1 = 1.f / (l10 + l11), w10 = l10 * i1, w11 = l11 * i1;
            uint4 o0, o1;
            const uint_t* p0 = (const uint_t*)&a0c0;
            const uint_t* p1 = (const uint_t*)&a0c1;
            const uint_t* q0 = (const uint_t*)&a1c0;
            const uint_t* q1 = (const uint_t*)&a1c1;
            uint_t* po = (uint_t*)&o0;
            uint_t* qo = (uint_t*)&o1;
#pragma unroll
            for (int j = 0; j < 4; j++) {
                fp16x2 u = *(const fp16x2*)&p0[j];
                fp16x2 v = *(const fp16x2*)&p1[j];
                po[j] = pk2h(w00 * (float)u.x + w01 * (float)v.x,
                             w00 * (float)u.y + w01 * (float)v.y);
                fp16x2 s = *(const fp16x2*)&q0[j];
                fp16x2 r = *(const fp16x2*)&q1[j];
                qo[j] = pk2h(w10 * (float)s.x + w11 * (float)r.x,
                             w10 * (float)s.y + w11 * (float)r.y);
            }
            *(uint4*)&As[cur][r0 * 40 + c8]        = o0;
            *(uint4*)&As[cur][(r0 + 64) * 40 + c8] = o1;
        }
        __syncthreads();     // As[cur] visible to all waves

        if (k0 + 32 < D_MODEL) {
            GLDS(Bg0 + k0 + 32, &Bs[nxt][segB]);
            PREFA(k0 + 32);
        }

        h16x8 af[4], bf[2];
#pragma unroll
        for (int mt = 0; mt < 4; mt++)
            af[mt] = *(const h16x8*)&As[cur][(wm + mt * 16 + l16) * 40 + quad * 8];
#pragma unroll
        for (int nt = 0; nt < 2; nt++)
            bf[nt] = *(const h16x8*)&Bs[cur][(wn + nt * 16 + l16) * 32 + fcol];
#pragma unroll
        for (int mt = 0; mt < 4; mt++)
#pragma unroll
            for (int nt = 0; nt < 2; nt++)
                acc[mt][nt] = MFMAH(af[mt], bf[nt], acc[mt][nt]);
    }
#undef PREFA

#pragma unroll
    for (int mt = 0; mt < 4; mt++)
#pragma unroll
        for (int nt = 0; nt < 2; nt++) {
            const int row = rowBase + wm + mt * 16 + quad * 4;
            const int col = colBase + wn + nt * 16 + l16;
#pragma unroll
            for (int r = 0; r < 4; r++)
                C[(size_t)(row + r) * D_MODEL + col] = acc[mt][nt][r];
        }
}

// ---------------------------------------------------------------------------
extern "C" void kernel_launch(void* const* d_in, const int* in_sizes, int n_in,
                              void* d_out, int out_size, void* d_ws, size_t ws_size,
                              hipStream_t stream)
{
    const float* x    = (const float*)d_in[0];
    const float* cosp = (const float*)d_in[1];
    const float* sinp = (const float*)d_in[2];
    const float* Wq   = (const float*)d_in[3];
    const float* Wk   = (const float*)d_in[4];
    const float* Wv   = (const float*)d_in[5];
    const float* Wo   = (const float*)d_in[6];

    char* w = (char*)d_ws;
    ushort_t* xb     = (ushort_t*)w;                       w += (size_t)MROWS * D_MODEL * 2;
    ushort_t* WqkvT  = (ushort_t*)w;                       w += (size_t)QKVN * D_MODEL * 2;
    ushort_t* WoT    = (ushort_t*)w;                       w += (size_t)D_MODEL * D_MODEL * 2;
    ushort_t* QKVh   = (ushort_t*)w;                       w += (size_t)MROWS * QKVN * 2;
    ushort_t* Kbuf   = (ushort_t*)w;                       w += (size_t)MROWS * KVDIM * 2;
    ushort_t* Vt     = (ushort_t*)w;                       w += (size_t)MROWS * KVDIM * 2;
    ushort_t* Pnum   = (ushort_t*)w;                       w += (size_t)NSPLIT * NTASK * 64 * 2;
    float*    Pl     = (float*)w;

    // --- fused prep (cast + 4 transposes): 1 dispatch
    prep_kernel<<<6656, 256, 0, stream>>>(x, Wq, Wk, Wv, Wo, xb, WqkvT, WoT);

    // --- fused QKV projection (f16 out), 128x64 tile
    gemm_qkv<<<dim3(QKVN / 64, MROWS / 128), 256, 0, stream>>>(
        xb, WqkvT, QKVh, MROWS, QKVN, D_MODEL);

    // --- fused K-rope + V transpose: 1 dispatch (Q-rope fused into attn)
    ropevt_kernel<<<NKBLK + 1024, 256, 0, stream>>>(
        QKVh, cosp, sinp, Kbuf, Vt);

    // --- attention (split-K x2, in-register PV, KVBLK=128, fused Q-rope)
    attn_mfma<<<dim3(NN / 256, NHEADS, BB * NSPLIT), 256, 0, stream>>>(
        QKVh, cosp, sinp, Kbuf, Vt, Pnum, Pl);

    // --- output projection with fused combine (fp32 out), 128x64 tile
    gemm_wo<<<dim3(D_MODEL / 64, MROWS / 128), 256, 0, stream>>>(
        Pnum, Pl, WoT, (float*)d_out);
}

// Round 11
// 194.429 us; speedup vs baseline: 1.0226x; 1.0226x over previous
//
#include <hip/hip_runtime.h>
#include <math.h>

#define D_MODEL 1024
#define NHEADS  16
#define NKV     4
#define HDIM    64
#define KVDIM   256
#define BB      2
#define NN      2048
#define MROWS   (BB*NN)        // 4096
#define QKVN    1536           // 1024 + 256 + 256
#define NTASK   (MROWS*NHEADS) // 65536
#define NSPLIT  4
#define KVBLK   128
#define NTILE   ((NN/NSPLIT)/KVBLK)   // 4

typedef unsigned short ushort_t;
typedef unsigned int uint_t;
typedef float    f32x4 __attribute__((ext_vector_type(4)));
typedef _Float16 h16x8 __attribute__((ext_vector_type(8)));
typedef _Float16 h16x4 __attribute__((ext_vector_type(4)));
typedef __fp16   fp16x2 __attribute__((ext_vector_type(2)));

#define MFMAH(A,B,C)  __builtin_amdgcn_mfma_f32_16x16x32_f16((A),(B),(C),0,0,0)
// NOTE spelling: carried-forward GCN-era intrinsic has NO underscore before f16
#define MFMA16(A,B,C) __builtin_amdgcn_mfma_f32_16x16x16f16((A),(B),(C),0,0,0)
// raw v_exp_f32 (1 instr) -- libm exp2f carries a ~6-instr denormal fixup
#define EXP2(x) __builtin_amdgcn_exp2f(x)

// async global->LDS, 16B per lane; LDS dest = wave-uniform base + lane*16
#define GLDS(gp, lp) __builtin_amdgcn_global_load_lds( \
    (const __attribute__((address_space(1))) void*)(gp), \
    (__attribute__((address_space(3))) void*)(lp), 16, 0, 0)

__device__ __forceinline__ ushort_t f2h(float f) {
    _Float16 h = (_Float16)f;
    return *(ushort_t*)&h;
}
__device__ __forceinline__ float h2f(ushort_t u) {
    return (float)(*(const _Float16*)&u);
}
// two fp32 -> packed f16x2, single v_cvt_pkrtz_f16_f32
__device__ __forceinline__ uint_t pk2h(float a, float b) {
    fp16x2 v = __builtin_amdgcn_cvt_pkrtz(a, b);
    return *(uint_t*)&v;
}

// ---------------------------------------------------------------------------
// Fused prep: cast x->f16 (blocks [0,4096)) + 4 weight transpose-casts
// (blocks [4096,6656)). One dispatch instead of five.
// ---------------------------------------------------------------------------
__global__ __launch_bounds__(256)
void prep_kernel(const float* __restrict__ x, const float* __restrict__ Wq,
                 const float* __restrict__ Wk, const float* __restrict__ Wv,
                 const float* __restrict__ Wo, ushort_t* __restrict__ xb,
                 ushort_t* __restrict__ WqkvT, ushort_t* __restrict__ WoT)
{
    __shared__ float T[32][33];
    int blk = blockIdx.x;
    if (blk < 4096) {                      // cast: 4096*256*4 = 4M elements
        const int i = blk * 256 + threadIdx.x;
        float4 v = ((const float4*)x)[i];
        uint2 o;
        o.x = pk2h(v.x, v.y);
        o.y = pk2h(v.z, v.w);
        ((uint2*)xb)[i] = o;
        return;
    }
    blk -= 4096;
    const float* src; ushort_t* dst; int N, bx, by;
    if (blk < 1024)      { src = Wq; dst = WqkvT;                            N = D_MODEL; bx = blk & 31; by = blk >> 5; }
    else if (blk < 1280) { blk -= 1024; src = Wk; dst = WqkvT + (size_t)1024 * D_MODEL; N = KVDIM; bx = blk & 7; by = blk >> 3; }
    else if (blk < 1536) { blk -= 1280; src = Wv; dst = WqkvT + (size_t)1280 * D_MODEL; N = KVDIM; bx = blk & 7; by = blk >> 3; }
    else                 { blk -= 1536; src = Wo; dst = WoT;                 N = D_MODEL; bx = blk & 31; by = blk >> 5; }
    const int tx = threadIdx.x & 31, ty = threadIdx.x >> 5;
    const int n0 = bx * 32, k0 = by * 32;
#pragma unroll
    for (int i = 0; i < 4; i++)
        T[ty + i * 8][tx] = src[(size_t)(k0 + ty + i * 8) * N + n0 + tx];
    __syncthreads();
#pragma unroll
    for (int i = 0; i < 4; i++)
        dst[(size_t)(n0 + ty + i * 8) * D_MODEL + k0 + tx] = f2h(T[tx][ty + i * 8]);
}

// ---------------------------------------------------------------------------
// Fused K-RoPE + V transpose (Q-rope lives in attn). One dispatch.
// Blocks [0, NKBLK): K rope; blocks [NKBLK, +1024): vtrans.
// ---------------------------------------------------------------------------
#define NKW (MROWS*NKV*32)      //   524,288
#define NKBLK (NKW / 256)       //   2048
__global__ __launch_bounds__(256)
void ropevt_kernel(const ushort_t* __restrict__ QKVh, const float* __restrict__ Cos,
                   const float* __restrict__ Sin, ushort_t* __restrict__ Kb,
                   ushort_t* __restrict__ Vt)
{
    __shared__ ushort_t T[32][34];
    if (blockIdx.x >= NKBLK) {
        const int blk2 = blockIdx.x - NKBLK;
        const int bx = blk2 & 63, by = (blk2 >> 6) & 7, b = blk2 >> 9;
        const int tx = threadIdx.x & 31, ty = threadIdx.x >> 5;
        const int n0 = bx * 32, d0 = by * 32;
#pragma unroll
        for (int i = 0; i < 4; i++)
            T[ty + i * 8][tx] =
                QKVh[(size_t)(b * NN + n0 + ty + i * 8) * QKVN + 1280 + d0 + tx];
        __syncthreads();
#pragma unroll
        for (int i = 0; i < 4; i++)
            Vt[(size_t)(b * 256 + d0 + ty + i * 8) * NN + n0 + tx] = T[tx][ty + i * 8];
        return;
    }
    const int i2 = blockIdx.x * 256 + threadIdx.x;
    const int row = i2 >> 7, rem = i2 & 127;
    const int h = rem >> 5, j = rem & 31;
    const int b = row >> 11, n = row & (NN - 1);
    const uint_t pr = *(const uint_t*)&QKVh[(size_t)row * QKVN + 1024 + h * 64 + 2 * j];
    const float e = h2f((ushort_t)pr), o = h2f((ushort_t)(pr >> 16));
    const float c = Cos[n * 32 + j], s = Sin[n * 32 + j];
    ushort_t* dst = Kb + ((size_t)(b * 4 + h) * NN + n) * 64;
    dst[j]      = f2h(e * c - o * s);
    dst[j + 32] = f2h(e * s + o * c);
}

// ---------------------------------------------------------------------------
// f16 MFMA GEMM (f16 out), 128x64 tile, GLDS + XOR swizzle + double-buffered
// LDS, one barrier/iter (round-8 proven config). Used for QKV projection.
// ---------------------------------------------------------------------------
__global__ __launch_bounds__(256)
void gemm_qkv(const ushort_t* __restrict__ A, const ushort_t* __restrict__ Bt,
              ushort_t* __restrict__ C, int M, int N, int K)
{
    __shared__ ushort_t As[2][128 * 32];
    __shared__ ushort_t Bs[2][64 * 32];

    const int tid  = threadIdx.x;
    const int wave = tid >> 6, lane = tid & 63;
    const int quad = lane >> 4, l16 = lane & 15;
    const int rowBase = blockIdx.y * 128, colBase = blockIdx.x * 64;
    const int wm = (wave >> 1) * 64, wn = (wave & 1) * 32;

    f32x4 acc[4][2];
    const f32x4 zz = {0.f, 0.f, 0.f, 0.f};
#pragma unroll
    for (int i = 0; i < 4; i++)
#pragma unroll
        for (int j = 0; j < 2; j++) acc[i][j] = zz;

    const int sr = wave * 32 + (lane >> 2);
    const int sc = ((lane & 3) ^ ((lane >> 3) & 3)) * 8;
    const ushort_t* Ag0 = A + (size_t)(rowBase + sr) * K + sc;
    const ushort_t* Ag1 = A + (size_t)(rowBase + sr + 16) * K + sc;
    const int segA0 = (wave * 2 + 0) * 512, segA1 = (wave * 2 + 1) * 512;
    const int br = wave * 16 + (lane >> 2);
    const ushort_t* Bg0 = Bt + (size_t)(colBase + br) * K + sc;
    const int segB = wave * 512;

    const int fcol = (quad ^ ((l16 >> 1) & 3)) * 8;

    GLDS(Ag0, &As[0][segA0]);
    GLDS(Ag1, &As[0][segA1]);
    GLDS(Bg0, &Bs[0][segB]);

    for (int k0 = 0; k0 < K; k0 += 32) {
        const int cur = (k0 >> 5) & 1, nxt = cur ^ 1;
        __syncthreads();
        if (k0 + 32 < K) {
            GLDS(Ag0 + k0 + 32, &As[nxt][segA0]);
            GLDS(Ag1 + k0 + 32, &As[nxt][segA1]);
            GLDS(Bg0 + k0 + 32, &Bs[nxt][segB]);
        }

        h16x8 af[4], bf[2];
#pragma unroll
        for (int mt = 0; mt < 4; mt++)
            af[mt] = *(const h16x8*)&As[cur][(wm + mt * 16 + l16) * 32 + fcol];
#pragma unroll
        for (int nt = 0; nt < 2; nt++)
            bf[nt] = *(const h16x8*)&Bs[cur][(wn + nt * 16 + l16) * 32 + fcol];
#pragma unroll
        for (int mt = 0; mt < 4; mt++)
#pragma unroll
            for (int nt = 0; nt < 2; nt++)
                acc[mt][nt] = MFMAH(af[mt], bf[nt], acc[mt][nt]);
    }

#pragma unroll
    for (int mt = 0; mt < 4; mt++)
#pragma unroll
        for (int nt = 0; nt < 2; nt++) {
            const int row = rowBase + wm + mt * 16 + quad * 4;
            const int col = colBase + wn + nt * 16 + l16;
#pragma unroll
            for (int r = 0; r < 4; r++)
                C[(size_t)(row + r) * N + col] = f2h(acc[mt][nt][r]);
        }
}

// ---------------------------------------------------------------------------
// MFMA flash attention. Round-23: NSPLIT 2->4 (grid 512->1024 blocks = 4
// blocks/CU resident; VGPR 124 and LDS 35.8KB both allow it -- the grid was
// the residency cap). QBLK=256 and per-tile structure UNCHANGED (4 tiles of
// 128 keys/block). Rationale: MfmaUtil 42 + VALU 35 at 2 waves/SIMD ==
// issue-slot starvation; r4's "NSPLIT=4 neutral" verdict was measured on
// the old P-LDS-chain kernel (confound now gone).
// Keeps: fused Q-rope, in-register K=16 PV, raw v_exp, MFMA denominator.
// ---------------------------------------------------------------------------
__global__ __launch_bounds__(256)
void attn_mfma(const ushort_t* __restrict__ QKVh, const float* __restrict__ Cos,
               const float* __restrict__ Sin, const ushort_t* __restrict__ Kb,
               const ushort_t* __restrict__ Vt, ushort_t* __restrict__ Pnum,
               float* __restrict__ Pl)
{
    const int qt = blockIdx.x, h = blockIdx.y;
    const int b = blockIdx.z >> 2, chunk = blockIdx.z & 3;
    const int kvh = h >> 2;
    const int tid = threadIdx.x;
    const int wave = tid >> 6, lane = tid & 63;
    const int quad = lane >> 4, l16 = lane & 15;

    __shared__ ushort_t Ks[128][72];
    __shared__ ushort_t Vs[64][136];

    const int row0 = qt * 256 + wave * 64;
    const float SC = 0.125f * 1.44269504f;

    h16x8 qf[4][2];
#pragma unroll
    for (int mt = 0; mt < 4; mt++) {
        const int n = row0 + mt * 16 + l16;
        // pre-rope Q row: cols h*64 + [2j, 2j+1] for j = quad*8 + i
        const uint_t* pr =
            (const uint_t*)(QKVh + (size_t)(b * NN + n) * QKVN + h * 64) + quad * 8;
        uint4 pa = *(const uint4*)pr;
        uint4 pc = *(const uint4*)(pr + 4);
        const uint_t pk[8] = {pa.x, pa.y, pa.z, pa.w, pc.x, pc.y, pc.z, pc.w};
        const float4 c0 = *(const float4*)&Cos[(size_t)n * 32 + quad * 8];
        const float4 c1 = *(const float4*)&Cos[(size_t)n * 32 + quad * 8 + 4];
        const float4 s0 = *(const float4*)&Sin[(size_t)n * 32 + quad * 8];
        const float4 s1 = *(const float4*)&Sin[(size_t)n * 32 + quad * 8 + 4];
        const float cc[8] = {c0.x, c0.y, c0.z, c0.w, c1.x, c1.y, c1.z, c1.w};
        const float ss[8] = {s0.x, s0.y, s0.z, s0.w, s1.x, s1.y, s1.z, s1.w};
#pragma unroll
        for (int i = 0; i < 8; i++) {
            const float e = h2f((ushort_t)pk[i]);
            const float o = h2f((ushort_t)(pk[i] >> 16));
            qf[mt][0][i] = (_Float16)((e * cc[i] - o * ss[i]) * SC);
            qf[mt][1][i] = (_Float16)((e * ss[i] + o * cc[i]) * SC);
        }
    }

    h16x4 ones;
#pragma unroll
    for (int i = 0; i < 4; i++) ones[i] = (_Float16)1.0f;

    const ushort_t* kbase = Kb + (size_t)(b * 4 + kvh) * NN * 64;
    const ushort_t* vbase = Vt + (size_t)(b * 256 + kvh * 64) * NN;
    const int key_lo = chunk * (NN / NSPLIT);          // 512-key chunk
    const int rot = (qt + ((h & 3) << 2)) & (NTILE - 1);

    const int srow = tid >> 2, sseg = (tid & 3) * 8;
    const ushort_t* kp_lane = kbase + (size_t)srow * 64 + sseg;   // + key*64
    const ushort_t* vp_lane = vbase + (size_t)srow * NN + sseg;   // + key

    const f32x4 zz = {0.f, 0.f, 0.f, 0.f};
    f32x4 o[4][4];
#pragma unroll
    for (int mt = 0; mt < 4; mt++)
#pragma unroll
        for (int dt = 0; dt < 4; dt++) o[mt][dt] = zz;
    f32x4 lsum[4];
#pragma unroll
    for (int mt = 0; mt < 4; mt++) lsum[mt] = zz;

    const int key0 = key_lo + rot * KVBLK;
    uint4 kreg0 = *(const uint4*)(kp_lane + (size_t)key0 * 64);
    uint4 kreg1 = *(const uint4*)(kp_lane + (size_t)key0 * 64 + 32);
    uint4 kreg2 = *(const uint4*)(kp_lane + (size_t)(key0 + 64) * 64);
    uint4 kreg3 = *(const uint4*)(kp_lane + (size_t)(key0 + 64) * 64 + 32);
    uint4 vreg0 = *(const uint4*)(vp_lane + key0);
    uint4 vreg1 = *(const uint4*)(vp_lane + key0 + 32);
    uint4 vreg2 = *(const uint4*)(vp_lane + key0 + 64);
    uint4 vreg3 = *(const uint4*)(vp_lane + key0 + 96);

    for (int t = 0; t < NTILE; t++) {
        __syncthreads();
        *(uint4*)&Ks[srow][sseg]           = kreg0;
        *(uint4*)&Ks[srow][sseg + 32]      = kreg1;
        *(uint4*)&Ks[srow + 64][sseg]      = kreg2;
        *(uint4*)&Ks[srow + 64][sseg + 32] = kreg3;
        *(uint4*)&Vs[srow][sseg]           = vreg0;
        *(uint4*)&Vs[srow][sseg + 32]      = vreg1;
        *(uint4*)&Vs[srow][sseg + 64]      = vreg2;
        *(uint4*)&Vs[srow][sseg + 96]      = vreg3;
        __syncthreads();

        if (t < NTILE - 1) {
            const int kn = key_lo + ((rot + t + 1) & (NTILE - 1)) * KVBLK;
            kreg0 = *(const uint4*)(kp_lane + (size_t)kn * 64);
            kreg1 = *(const uint4*)(kp_lane + (size_t)kn * 64 + 32);
            kreg2 = *(const uint4*)(kp_lane + (size_t)(kn + 64) * 64);
            kreg3 = *(const uint4*)(kp_lane + (size_t)(kn + 64) * 64 + 32);
            vreg0 = *(const uint4*)(vp_lane + kn);
            vreg1 = *(const uint4*)(vp_lane + kn + 32);
            vreg2 = *(const uint4*)(vp_lane + kn + 64);
            vreg3 = *(const uint4*)(vp_lane + kn + 96);
        }

        // ---- fused per-kt: S^T = K Q^T -> exp2 -> pack -> PV (K=16, P in regs)
#pragma unroll
        for (int kt = 0; kt < 8; kt++) {
            h16x8 kf0 = *(const h16x8*)&Ks[kt * 16 + l16][quad * 8];
            h16x8 kf1 = *(const h16x8*)&Ks[kt * 16 + l16][32 + quad * 8];
            // V fragments for this kt: A-layout (K=16) = Vt[d][kt*16+quad*4+i]
            h16x4 va[4];
#pragma unroll
            for (int dt = 0; dt < 4; dt++)
                va[dt] = *(const h16x4*)&Vs[dt * 16 + l16][kt * 16 + quad * 4];

            uint2 pb[4];
#pragma unroll
            for (int mt = 0; mt < 4; mt++) {
                f32x4 st = MFMAH(kf0, qf[mt][0], zz);
                st = MFMAH(kf1, qf[mt][1], st);
                pb[mt].x = pk2h(EXP2(st[0]), EXP2(st[1]));
                pb[mt].y = pk2h(EXP2(st[2]), EXP2(st[3]));
            }
#pragma unroll
            for (int mt = 0; mt < 4; mt++) {
                const h16x4 pbv = *(const h16x4*)&pb[mt];
#pragma unroll
                for (int dt = 0; dt < 4; dt++)
                    o[mt][dt] = MFMA16(va[dt], pbv, o[mt][dt]);
                lsum[mt] = MFMA16(ones, pbv, lsum[mt]);
            }
        }
    }

    const size_t task0 = (size_t)(b * 16 + h) * NN + row0;
    ushort_t* np = Pnum + ((size_t)chunk * NTASK + task0) * 64;
#pragma unroll
    for (int mt = 0; mt < 4; mt++) {
        const float lt = lsum[mt][0];    // denom for q=l16 (rows identical)
        const float inv = 1.0f / lt;
#pragma unroll
        for (int dt = 0; dt < 4; dt++) {
            f32x4 v = o[mt][dt];
            uint2 pk;
            pk.x = pk2h(v[0] * inv, v[1] * inv);
            pk.y = pk2h(v[2] * inv, v[3] * inv);
            *(uint2*)&np[(size_t)(mt * 16 + l16) * 64 + dt * 16 + quad * 4] = pk;
        }
        if (quad == 0)
            Pl[(size_t)chunk * NTASK + task0 + mt * 16 + l16] = lt;
    }
}

// ---------------------------------------------------------------------------
// Split-K combine (4-way) + relayout to plain [row][D_MODEL] f16 matrix.
// Each thread: 8 contiguous f16 of one head-block. 42MB traffic, ~7us.
// ---------------------------------------------------------------------------
__global__ __launch_bounds__(256)
void combine_kernel(const ushort_t* __restrict__ Pnum, const float* __restrict__ Pl,
                    ushort_t* __restrict__ Ob)
{
    const uint_t i = blockIdx.x * 256 + threadIdx.x;   // 8-elem group, 524288 total
    const int row = i >> 7;            // 128 groups per 1024-col row
    const int g = i & 127;
    const int col0 = g * 8;
    const int h = col0 >> 6, d = col0 & 63;
    const int b = row >> 11, n = row & (NN - 1);
    const size_t task = ((size_t)(b * 16 + h) << 11) + n;

    float l[4], tot = 0.f;
#pragma unroll
    for (int c = 0; c < 4; c++) { l[c] = Pl[(size_t)c * NTASK + task]; tot += l[c]; }
    const float inv = 1.f / tot;

    uint4 in[4];
#pragma unroll
    for (int c = 0; c < 4; c++)
        in[c] = *(const uint4*)&Pnum[((size_t)c * NTASK + task) * 64 + d];

    uint4 out;
    uint_t* po = (uint_t*)&out;
#pragma unroll
    for (int j = 0; j < 4; j++) {
        float x = 0.f, y = 0.f;
#pragma unroll
        for (int c = 0; c < 4; c++) {
            const float w = l[c] * inv;
            fp16x2 u = *(const fp16x2*)&((const uint_t*)&in[c])[j];
            x += w * (float)u.x;
            y += w * (float)u.y;
        }
        po[j] = pk2h(x, y);
    }
    *(uint4*)&Ob[(size_t)row * D_MODEL + col0] = out;
}

// ---------------------------------------------------------------------------
// Wo GEMM: plain f16 GEMM (fp32 out), 128x64 tile -- gemm_qkv structure
// verbatim (GLDS A+B staging, 1 barrier/iter). Combine moved to its own
// kernel; this deletes the 2-barrier combine-staging variant.
// ---------------------------------------------------------------------------
__global__ __launch_bounds__(256)
void gemm_wo(const ushort_t* __restrict__ A, const ushort_t* __restrict__ Bt,
             float* __restrict__ C)
{
    __shared__ ushort_t As[2][128 * 32];
    __shared__ ushort_t Bs[2][64 * 32];

    const int tid  = threadIdx.x;
    const int wave = tid >> 6, lane = tid & 63;
    const int quad = lane >> 4, l16 = lane & 15;
    const int rowBase = blockIdx.y * 128, colBase = blockIdx.x * 64;
    const int wm = (wave >> 1) * 64, wn = (wave & 1) * 32;

    f32x4 acc[4][2];
    const f32x4 zz = {0.f, 0.f, 0.f, 0.f};
#pragma unroll
    for (int i = 0; i < 4; i++)
#pragma unroll
        for (int j = 0; j < 2; j++) acc[i][j] = zz;

    const int sr = wave * 32 + (lane >> 2);
    const int sc = ((lane & 3) ^ ((lane >> 3) & 3)) * 8;
    const ushort_t* Ag0 = A + (size_t)(rowBase + sr) * D_MODEL + sc;
    const ushort_t* Ag1 = A + (size_t)(rowBase + sr + 16) * D_MODEL + sc;
    const int segA0 = (wave * 2 + 0) * 512, segA1 = (wave * 2 + 1) * 512;
    const int br = wave * 16 + (lane >> 2);
    const ushort_t* Bg0 = Bt + (size_t)(colBase + br) * D_MODEL + sc;
    const int segB = wave * 512;

    const int fcol = (quad ^ ((l16 >> 1) & 3)) * 8;

    GLDS(Ag0, &As[0][segA0]);
    GLDS(Ag1, &As[0][segA1]);
    GLDS(Bg0, &Bs[0][segB]);

    for (int k0 = 0; k0 < D_MODEL; k0 += 32) {
        const int cur = (k0 >> 5) & 1, nxt = cur ^ 1;
        __syncthreads();
        if (k0 + 32 < D_MODEL) {
            GLDS(Ag0 + k0 + 32, &As[nxt][segA0]);
            GLDS(Ag1 + k0 + 32, &As[nxt][segA1]);
            GLDS(Bg0 + k0 + 32, &Bs[nxt][segB]);
        }

        h16x8 af[4], bf[2];
#pragma unroll
        for (int mt = 0; mt < 4; mt++)
            af[mt] = *(const h16x8*)&As[cur][(wm + mt * 16 + l16) * 32 + fcol];
#pragma unroll
        for (int nt = 0; nt < 2; nt++)
            bf[nt] = *(const h16x8*)&Bs[cur][(wn + nt * 16 + l16) * 32 + fcol];
#pragma unroll
        for (int mt = 0; mt < 4; mt++)
#pragma unroll
            for (int nt = 0; nt < 2; nt++)
                acc[mt][nt] = MFMAH(af[mt], bf[nt], acc[mt][nt]);
    }

#pragma unroll
    for (int mt = 0; mt < 4; mt++)
#pragma unroll
        for (int nt = 0; nt < 2; nt++) {
            const int row = rowBase + wm + mt * 16 + quad * 4;
            const int col = colBase + wn + nt * 16 + l16;
#pragma unroll
            for (int r = 0; r < 4; r++)
                C[(size_t)(row + r) * D_MODEL + col] = acc[mt][nt][r];
        }
}

// ---------------------------------------------------------------------------
extern "C" void kernel_launch(void* const* d_in, const int* in_sizes, int n_in,
                              void* d_out, int out_size, void* d_ws, size_t ws_size,
                              hipStream_t stream)
{
    const float* x    = (const float*)d_in[0];
    const float* cosp = (const float*)d_in[1];
    const float* sinp = (const float*)d_in[2];
    const float* Wq   = (const float*)d_in[3];
    const float* Wk   = (const float*)d_in[4];
    const float* Wv   = (const float*)d_in[5];
    const float* Wo   = (const float*)d_in[6];

    char* w = (char*)d_ws;
    ushort_t* xb     = (ushort_t*)w;                       w += (size_t)MROWS * D_MODEL * 2;
    ushort_t* WqkvT  = (ushort_t*)w;                       w += (size_t)QKVN * D_MODEL * 2;
    ushort_t* WoT    = (ushort_t*)w;                       w += (size_t)D_MODEL * D_MODEL * 2;
    ushort_t* QKVh   = (ushort_t*)w;                       w += (size_t)MROWS * QKVN * 2;
    ushort_t* Kbuf   = (ushort_t*)w;                       w += (size_t)MROWS * KVDIM * 2;
    ushort_t* Vt     = (ushort_t*)w;                       w += (size_t)MROWS * KVDIM * 2;
    ushort_t* Obuf   = (ushort_t*)w;                       w += (size_t)MROWS * D_MODEL * 2;
    ushort_t* Pnum   = (ushort_t*)w;                       w += (size_t)NSPLIT * NTASK * 64 * 2;
    float*    Pl     = (float*)w;

    // --- fused prep (cast + 4 transposes): 1 dispatch
    prep_kernel<<<6656, 256, 0, stream>>>(x, Wq, Wk, Wv, Wo, xb, WqkvT, WoT);

    // --- fused QKV projection (f16 out), 128x64 tile
    gemm_qkv<<<dim3(QKVN / 64, MROWS / 128), 256, 0, stream>>>(
        xb, WqkvT, QKVh, MROWS, QKVN, D_MODEL);

    // --- fused K-rope + V transpose: 1 dispatch (Q-rope fused into attn)
    ropevt_kernel<<<NKBLK + 1024, 256, 0, stream>>>(
        QKVh, cosp, sinp, Kbuf, Vt);

    // --- attention (split-K x4 -> 1024 blocks = 4/CU, in-register PV)
    attn_mfma<<<dim3(NN / 256, NHEADS, BB * NSPLIT), 256, 0, stream>>>(
        QKVh, cosp, sinp, Kbuf, Vt, Pnum, Pl);

    // --- 4-way split-K combine -> plain f16 matrix
    combine_kernel<<<(MROWS * D_MODEL / 8) / 256, 256, 0, stream>>>(
        Pnum, Pl, Obuf);

    // --- output projection (plain GEMM, fp32 out), 128x64 tile
    gemm_wo<<<dim3(D_MODEL / 64, MROWS / 128), 256, 0, stream>>>(
        Obuf, WoT, (float*)d_out);
}

// Round 12
// 190.710 us; speedup vs baseline: 1.0426x; 1.0195x over previous
//
#include <hip/hip_runtime.h>
#include <math.h>

#define D_MODEL 1024
#define NHEADS  16
#define NKV     4
#define HDIM    64
#define KVDIM   256
#define BB      2
#define NN      2048
#define MROWS   (BB*NN)        // 4096
#define QKVN    1536           // 1024 + 256 + 256
#define NTASK   (MROWS*NHEADS) // 65536
#define NSPLIT  2
#define KVBLK   128
#define NTILE   ((NN/NSPLIT)/KVBLK)   // 8

typedef unsigned short ushort_t;
typedef unsigned int uint_t;
typedef float    f32x4 __attribute__((ext_vector_type(4)));
typedef _Float16 h16x8 __attribute__((ext_vector_type(8)));
typedef _Float16 h16x4 __attribute__((ext_vector_type(4)));
typedef __fp16   fp16x2 __attribute__((ext_vector_type(2)));

#define MFMAH(A,B,C)  __builtin_amdgcn_mfma_f32_16x16x32_f16((A),(B),(C),0,0,0)
// NOTE spelling: carried-forward GCN-era intrinsic has NO underscore before f16
#define MFMA16(A,B,C) __builtin_amdgcn_mfma_f32_16x16x16f16((A),(B),(C),0,0,0)
// raw v_exp_f32 (1 instr) -- libm exp2f carries a ~6-instr denormal fixup
#define EXP2(x) __builtin_amdgcn_exp2f(x)

// async global->LDS, 16B per lane; LDS dest = wave-uniform base + lane*16
#define GLDS(gp, lp) __builtin_amdgcn_global_load_lds( \
    (const __attribute__((address_space(1))) void*)(gp), \
    (__attribute__((address_space(3))) void*)(lp), 16, 0, 0)

__device__ __forceinline__ ushort_t f2h(float f) {
    _Float16 h = (_Float16)f;
    return *(ushort_t*)&h;
}
__device__ __forceinline__ float h2f(ushort_t u) {
    return (float)(*(const _Float16*)&u);
}
// two fp32 -> packed f16x2, single v_cvt_pkrtz_f16_f32
__device__ __forceinline__ uint_t pk2h(float a, float b) {
    fp16x2 v = __builtin_amdgcn_cvt_pkrtz(a, b);
    return *(uint_t*)&v;
}

// ---------------------------------------------------------------------------
// Fused prep: cast x->f16 (blocks [0,4096)) + 4 weight transpose-casts
// (blocks [4096,6656)). One dispatch instead of five.
// ---------------------------------------------------------------------------
__global__ __launch_bounds__(256)
void prep_kernel(const float* __restrict__ x, const float* __restrict__ Wq,
                 const float* __restrict__ Wk, const float* __restrict__ Wv,
                 const float* __restrict__ Wo, ushort_t* __restrict__ xb,
                 ushort_t* __restrict__ WqkvT, ushort_t* __restrict__ WoT)
{
    __shared__ float T[32][33];
    int blk = blockIdx.x;
    if (blk < 4096) {                      // cast: 4096*256*4 = 4M elements
        const int i = blk * 256 + threadIdx.x;
        float4 v = ((const float4*)x)[i];
        uint2 o;
        o.x = pk2h(v.x, v.y);
        o.y = pk2h(v.z, v.w);
        ((uint2*)xb)[i] = o;
        return;
    }
    blk -= 4096;
    const float* src; ushort_t* dst; int N, bx, by;
    if (blk < 1024)      { src = Wq; dst = WqkvT;                            N = D_MODEL; bx = blk & 31; by = blk >> 5; }
    else if (blk < 1280) { blk -= 1024; src = Wk; dst = WqkvT + (size_t)1024 * D_MODEL; N = KVDIM; bx = blk & 7; by = blk >> 3; }
    else if (blk < 1536) { blk -= 1280; src = Wv; dst = WqkvT + (size_t)1280 * D_MODEL; N = KVDIM; bx = blk & 7; by = blk >> 3; }
    else                 { blk -= 1536; src = Wo; dst = WoT;                 N = D_MODEL; bx = blk & 31; by = blk >> 5; }
    const int tx = threadIdx.x & 31, ty = threadIdx.x >> 5;
    const int n0 = bx * 32, k0 = by * 32;
#pragma unroll
    for (int i = 0; i < 4; i++)
        T[ty + i * 8][tx] = src[(size_t)(k0 + ty + i * 8) * N + n0 + tx];
    __syncthreads();
#pragma unroll
    for (int i = 0; i < 4; i++)
        dst[(size_t)(n0 + ty + i * 8) * D_MODEL + k0 + tx] = f2h(T[tx][ty + i * 8]);
}

// ---------------------------------------------------------------------------
// Fused K-RoPE + V transpose (Q-rope lives in attn). One dispatch.
// Blocks [0, NKBLK): K rope; blocks [NKBLK, +1024): vtrans.
// ---------------------------------------------------------------------------
#define NKW (MROWS*NKV*32)      //   524,288
#define NKBLK (NKW / 256)       //   2048
__global__ __launch_bounds__(256)
void ropevt_kernel(const ushort_t* __restrict__ QKVh, const float* __restrict__ Cos,
                   const float* __restrict__ Sin, ushort_t* __restrict__ Kb,
                   ushort_t* __restrict__ Vt)
{
    __shared__ ushort_t T[32][34];
    if (blockIdx.x >= NKBLK) {
        const int blk2 = blockIdx.x - NKBLK;
        const int bx = blk2 & 63, by = (blk2 >> 6) & 7, b = blk2 >> 9;
        const int tx = threadIdx.x & 31, ty = threadIdx.x >> 5;
        const int n0 = bx * 32, d0 = by * 32;
#pragma unroll
        for (int i = 0; i < 4; i++)
            T[ty + i * 8][tx] =
                QKVh[(size_t)(b * NN + n0 + ty + i * 8) * QKVN + 1280 + d0 + tx];
        __syncthreads();
#pragma unroll
        for (int i = 0; i < 4; i++)
            Vt[(size_t)(b * 256 + d0 + ty + i * 8) * NN + n0 + tx] = T[tx][ty + i * 8];
        return;
    }
    const int i2 = blockIdx.x * 256 + threadIdx.x;
    const int row = i2 >> 7, rem = i2 & 127;
    const int h = rem >> 5, j = rem & 31;
    const int b = row >> 11, n = row & (NN - 1);
    const uint_t pr = *(const uint_t*)&QKVh[(size_t)row * QKVN + 1024 + h * 64 + 2 * j];
    const float e = h2f((ushort_t)pr), o = h2f((ushort_t)(pr >> 16));
    const float c = Cos[n * 32 + j], s = Sin[n * 32 + j];
    ushort_t* dst = Kb + ((size_t)(b * 4 + h) * NN + n) * 64;
    dst[j]      = f2h(e * c - o * s);
    dst[j + 32] = f2h(e * s + o * c);
}

// ---------------------------------------------------------------------------
// f16 MFMA GEMM (f16 out), 128x64 tile, GLDS + XOR swizzle + double-buffered
// LDS, one barrier/iter (round-8 proven config). Used for QKV projection.
// ---------------------------------------------------------------------------
__global__ __launch_bounds__(256)
void gemm_qkv(const ushort_t* __restrict__ A, const ushort_t* __restrict__ Bt,
              ushort_t* __restrict__ C, int M, int N, int K)
{
    __shared__ ushort_t As[2][128 * 32];
    __shared__ ushort_t Bs[2][64 * 32];

    const int tid  = threadIdx.x;
    const int wave = tid >> 6, lane = tid & 63;
    const int quad = lane >> 4, l16 = lane & 15;
    const int rowBase = blockIdx.y * 128, colBase = blockIdx.x * 64;
    const int wm = (wave >> 1) * 64, wn = (wave & 1) * 32;

    f32x4 acc[4][2];
    const f32x4 zz = {0.f, 0.f, 0.f, 0.f};
#pragma unroll
    for (int i = 0; i < 4; i++)
#pragma unroll
        for (int j = 0; j < 2; j++) acc[i][j] = zz;

    const int sr = wave * 32 + (lane >> 2);
    const int sc = ((lane & 3) ^ ((lane >> 3) & 3)) * 8;
    const ushort_t* Ag0 = A + (size_t)(rowBase + sr) * K + sc;
    const ushort_t* Ag1 = A + (size_t)(rowBase + sr + 16) * K + sc;
    const int segA0 = (wave * 2 + 0) * 512, segA1 = (wave * 2 + 1) * 512;
    const int br = wave * 16 + (lane >> 2);
    const ushort_t* Bg0 = Bt + (size_t)(colBase + br) * K + sc;
    const int segB = wave * 512;

    const int fcol = (quad ^ ((l16 >> 1) & 3)) * 8;

    GLDS(Ag0, &As[0][segA0]);
    GLDS(Ag1, &As[0][segA1]);
    GLDS(Bg0, &Bs[0][segB]);

    for (int k0 = 0; k0 < K; k0 += 32) {
        const int cur = (k0 >> 5) & 1, nxt = cur ^ 1;
        __syncthreads();
        if (k0 + 32 < K) {
            GLDS(Ag0 + k0 + 32, &As[nxt][segA0]);
            GLDS(Ag1 + k0 + 32, &As[nxt][segA1]);
            GLDS(Bg0 + k0 + 32, &Bs[nxt][segB]);
        }

        h16x8 af[4], bf[2];
#pragma unroll
        for (int mt = 0; mt < 4; mt++)
            af[mt] = *(const h16x8*)&As[cur][(wm + mt * 16 + l16) * 32 + fcol];
#pragma unroll
        for (int nt = 0; nt < 2; nt++)
            bf[nt] = *(const h16x8*)&Bs[cur][(wn + nt * 16 + l16) * 32 + fcol];
#pragma unroll
        for (int mt = 0; mt < 4; mt++)
#pragma unroll
            for (int nt = 0; nt < 2; nt++)
                acc[mt][nt] = MFMAH(af[mt], bf[nt], acc[mt][nt]);
    }

#pragma unroll
    for (int mt = 0; mt < 4; mt++)
#pragma unroll
        for (int nt = 0; nt < 2; nt++) {
            const int row = rowBase + wm + mt * 16 + quad * 4;
            const int col = colBase + wn + nt * 16 + l16;
#pragma unroll
            for (int r = 0; r < 4; r++)
                C[(size_t)(row + r) * N + col] = f2h(acc[mt][nt][r]);
        }
}

// ---------------------------------------------------------------------------
// MFMA flash attention. Round-24: NSPLIT back to 2 (r11 proved residency
// never rises past ~18% regardless of grid -- per-CU limited; extra blocks
// only add per-block overhead). Keeps r10's attn verbatim: fused Q-rope,
// in-register K=16 PV, raw v_exp, KVBLK=128 (8 tiles), MFMA denominator,
// 2 barriers/tile.
// ---------------------------------------------------------------------------
__global__ __launch_bounds__(256)
void attn_mfma(const ushort_t* __restrict__ QKVh, const float* __restrict__ Cos,
               const float* __restrict__ Sin, const ushort_t* __restrict__ Kb,
               const ushort_t* __restrict__ Vt, ushort_t* __restrict__ Pnum,
               float* __restrict__ Pl)
{
    const int qt = blockIdx.x, h = blockIdx.y;
    const int b = blockIdx.z >> 1, chunk = blockIdx.z & 1;
    const int kvh = h >> 2;
    const int tid = threadIdx.x;
    const int wave = tid >> 6, lane = tid & 63;
    const int quad = lane >> 4, l16 = lane & 15;

    __shared__ ushort_t Ks[128][72];
    __shared__ ushort_t Vs[64][136];

    const int row0 = qt * 256 + wave * 64;
    const float SC = 0.125f * 1.44269504f;

    h16x8 qf[4][2];
#pragma unroll
    for (int mt = 0; mt < 4; mt++) {
        const int n = row0 + mt * 16 + l16;
        // pre-rope Q row: cols h*64 + [2j, 2j+1] for j = quad*8 + i
        const uint_t* pr =
            (const uint_t*)(QKVh + (size_t)(b * NN + n) * QKVN + h * 64) + quad * 8;
        uint4 pa = *(const uint4*)pr;
        uint4 pc = *(const uint4*)(pr + 4);
        const uint_t pk[8] = {pa.x, pa.y, pa.z, pa.w, pc.x, pc.y, pc.z, pc.w};
        const float4 c0 = *(const float4*)&Cos[(size_t)n * 32 + quad * 8];
        const float4 c1 = *(const float4*)&Cos[(size_t)n * 32 + quad * 8 + 4];
        const float4 s0 = *(const float4*)&Sin[(size_t)n * 32 + quad * 8];
        const float4 s1 = *(const float4*)&Sin[(size_t)n * 32 + quad * 8 + 4];
        const float cc[8] = {c0.x, c0.y, c0.z, c0.w, c1.x, c1.y, c1.z, c1.w};
        const float ss[8] = {s0.x, s0.y, s0.z, s0.w, s1.x, s1.y, s1.z, s1.w};
#pragma unroll
        for (int i = 0; i < 8; i++) {
            const float e = h2f((ushort_t)pk[i]);
            const float o = h2f((ushort_t)(pk[i] >> 16));
            qf[mt][0][i] = (_Float16)((e * cc[i] - o * ss[i]) * SC);
            qf[mt][1][i] = (_Float16)((e * ss[i] + o * cc[i]) * SC);
        }
    }

    h16x4 ones;
#pragma unroll
    for (int i = 0; i < 4; i++) ones[i] = (_Float16)1.0f;

    const ushort_t* kbase = Kb + (size_t)(b * 4 + kvh) * NN * 64;
    const ushort_t* vbase = Vt + (size_t)(b * 256 + kvh * 64) * NN;
    const int key_lo = chunk * (NN / NSPLIT);          // 1024-key chunk
    const int rot = (qt + ((h & 3) << 2)) & (NTILE - 1);

    const int srow = tid >> 2, sseg = (tid & 3) * 8;
    const ushort_t* kp_lane = kbase + (size_t)srow * 64 + sseg;   // + key*64
    const ushort_t* vp_lane = vbase + (size_t)srow * NN + sseg;   // + key

    const f32x4 zz = {0.f, 0.f, 0.f, 0.f};
    f32x4 o[4][4];
#pragma unroll
    for (int mt = 0; mt < 4; mt++)
#pragma unroll
        for (int dt = 0; dt < 4; dt++) o[mt][dt] = zz;
    f32x4 lsum[4];
#pragma unroll
    for (int mt = 0; mt < 4; mt++) lsum[mt] = zz;

    const int key0 = key_lo + rot * KVBLK;
    uint4 kreg0 = *(const uint4*)(kp_lane + (size_t)key0 * 64);
    uint4 kreg1 = *(const uint4*)(kp_lane + (size_t)key0 * 64 + 32);
    uint4 kreg2 = *(const uint4*)(kp_lane + (size_t)(key0 + 64) * 64);
    uint4 kreg3 = *(const uint4*)(kp_lane + (size_t)(key0 + 64) * 64 + 32);
    uint4 vreg0 = *(const uint4*)(vp_lane + key0);
    uint4 vreg1 = *(const uint4*)(vp_lane + key0 + 32);
    uint4 vreg2 = *(const uint4*)(vp_lane + key0 + 64);
    uint4 vreg3 = *(const uint4*)(vp_lane + key0 + 96);

    for (int t = 0; t < NTILE; t++) {
        __syncthreads();
        *(uint4*)&Ks[srow][sseg]           = kreg0;
        *(uint4*)&Ks[srow][sseg + 32]      = kreg1;
        *(uint4*)&Ks[srow + 64][sseg]      = kreg2;
        *(uint4*)&Ks[srow + 64][sseg + 32] = kreg3;
        *(uint4*)&Vs[srow][sseg]           = vreg0;
        *(uint4*)&Vs[srow][sseg + 32]      = vreg1;
        *(uint4*)&Vs[srow][sseg + 64]      = vreg2;
        *(uint4*)&Vs[srow][sseg + 96]      = vreg3;
        __syncthreads();

        if (t < NTILE - 1) {
            const int kn = key_lo + ((rot + t + 1) & (NTILE - 1)) * KVBLK;
            kreg0 = *(const uint4*)(kp_lane + (size_t)kn * 64);
            kreg1 = *(const uint4*)(kp_lane + (size_t)kn * 64 + 32);
            kreg2 = *(const uint4*)(kp_lane + (size_t)(kn + 64) * 64);
            kreg3 = *(const uint4*)(kp_lane + (size_t)(kn + 64) * 64 + 32);
            vreg0 = *(const uint4*)(vp_lane + kn);
            vreg1 = *(const uint4*)(vp_lane + kn + 32);
            vreg2 = *(const uint4*)(vp_lane + kn + 64);
            vreg3 = *(const uint4*)(vp_lane + kn + 96);
        }

        // ---- fused per-kt: S^T = K Q^T -> exp2 -> pack -> PV (K=16, P in regs)
#pragma unroll
        for (int kt = 0; kt < 8; kt++) {
            h16x8 kf0 = *(const h16x8*)&Ks[kt * 16 + l16][quad * 8];
            h16x8 kf1 = *(const h16x8*)&Ks[kt * 16 + l16][32 + quad * 8];
            // V fragments for this kt: A-layout (K=16) = Vt[d][kt*16+quad*4+i]
            h16x4 va[4];
#pragma unroll
            for (int dt = 0; dt < 4; dt++)
                va[dt] = *(const h16x4*)&Vs[dt * 16 + l16][kt * 16 + quad * 4];

            uint2 pb[4];
#pragma unroll
            for (int mt = 0; mt < 4; mt++) {
                f32x4 st = MFMAH(kf0, qf[mt][0], zz);
                st = MFMAH(kf1, qf[mt][1], st);
                pb[mt].x = pk2h(EXP2(st[0]), EXP2(st[1]));
                pb[mt].y = pk2h(EXP2(st[2]), EXP2(st[3]));
            }
#pragma unroll
            for (int mt = 0; mt < 4; mt++) {
                const h16x4 pbv = *(const h16x4*)&pb[mt];
#pragma unroll
                for (int dt = 0; dt < 4; dt++)
                    o[mt][dt] = MFMA16(va[dt], pbv, o[mt][dt]);
                lsum[mt] = MFMA16(ones, pbv, lsum[mt]);
            }
        }
    }

    const size_t task0 = (size_t)(b * 16 + h) * NN + row0;
    ushort_t* np = Pnum + ((size_t)chunk * NTASK + task0) * 64;
#pragma unroll
    for (int mt = 0; mt < 4; mt++) {
        const float lt = lsum[mt][0];    // denom for q=l16 (rows identical)
        const float inv = 1.0f / lt;
#pragma unroll
        for (int dt = 0; dt < 4; dt++) {
            f32x4 v = o[mt][dt];
            uint2 pk;
            pk.x = pk2h(v[0] * inv, v[1] * inv);
            pk.y = pk2h(v[2] * inv, v[3] * inv);
            *(uint2*)&np[(size_t)(mt * 16 + l16) * 64 + dt * 16 + quad * 4] = pk;
        }
        if (quad == 0)
            Pl[(size_t)chunk * NTASK + task0 + mt * 16 + l16] = lt;
    }
}

// ---------------------------------------------------------------------------
// Split-K combine (2-way) + relayout to plain [row][D_MODEL] f16 matrix.
// Each thread: 8 contiguous f16 of one head-block. ~21MB traffic, ~4us.
// ---------------------------------------------------------------------------
__global__ __launch_bounds__(256)
void combine_kernel(const ushort_t* __restrict__ Pnum, const float* __restrict__ Pl,
                    ushort_t* __restrict__ Ob)
{
    const uint_t i = blockIdx.x * 256 + threadIdx.x;   // 8-elem group, 524288 total
    const int row = i >> 7;            // 128 groups per 1024-col row
    const int g = i & 127;
    const int col0 = g * 8;
    const int h = col0 >> 6, d = col0 & 63;
    const int b = row >> 11, n = row & (NN - 1);
    const size_t task = ((size_t)(b * 16 + h) << 11) + n;

    float l[NSPLIT], tot = 0.f;
#pragma unroll
    for (int c = 0; c < NSPLIT; c++) { l[c] = Pl[(size_t)c * NTASK + task]; tot += l[c]; }
    const float inv = 1.f / tot;

    uint4 in[NSPLIT];
#pragma unroll
    for (int c = 0; c < NSPLIT; c++)
        in[c] = *(const uint4*)&Pnum[((size_t)c * NTASK + task) * 64 + d];

    uint4 out;
    uint_t* po = (uint_t*)&out;
#pragma unroll
    for (int j = 0; j < 4; j++) {
        float x = 0.f, y = 0.f;
#pragma unroll
        for (int c = 0; c < NSPLIT; c++) {
            const float w = l[c] * inv;
            fp16x2 u = *(const fp16x2*)&((const uint_t*)&in[c])[j];
            x += w * (float)u.x;
            y += w * (float)u.y;
        }
        po[j] = pk2h(x, y);
    }
    *(uint4*)&Ob[(size_t)row * D_MODEL + col0] = out;
}

// ---------------------------------------------------------------------------
// Wo GEMM: plain f16 GEMM (fp32 out), 128x64 tile -- gemm_qkv structure
// verbatim (GLDS A+B staging, 1 barrier/iter).
// ---------------------------------------------------------------------------
__global__ __launch_bounds__(256)
void gemm_wo(const ushort_t* __restrict__ A, const ushort_t* __restrict__ Bt,
             float* __restrict__ C)
{
    __shared__ ushort_t As[2][128 * 32];
    __shared__ ushort_t Bs[2][64 * 32];

    const int tid  = threadIdx.x;
    const int wave = tid >> 6, lane = tid & 63;
    const int quad = lane >> 4, l16 = lane & 15;
    const int rowBase = blockIdx.y * 128, colBase = blockIdx.x * 64;
    const int wm = (wave >> 1) * 64, wn = (wave & 1) * 32;

    f32x4 acc[4][2];
    const f32x4 zz = {0.f, 0.f, 0.f, 0.f};
#pragma unroll
    for (int i = 0; i < 4; i++)
#pragma unroll
        for (int j = 0; j < 2; j++) acc[i][j] = zz;

    const int sr = wave * 32 + (lane >> 2);
    const int sc = ((lane & 3) ^ ((lane >> 3) & 3)) * 8;
    const ushort_t* Ag0 = A + (size_t)(rowBase + sr) * D_MODEL + sc;
    const ushort_t* Ag1 = A + (size_t)(rowBase + sr + 16) * D_MODEL + sc;
    const int segA0 = (wave * 2 + 0) * 512, segA1 = (wave * 2 + 1) * 512;
    const int br = wave * 16 + (lane >> 2);
    const ushort_t* Bg0 = Bt + (size_t)(colBase + br) * D_MODEL + sc;
    const int segB = wave * 512;

    const int fcol = (quad ^ ((l16 >> 1) & 3)) * 8;

    GLDS(Ag0, &As[0][segA0]);
    GLDS(Ag1, &As[0][segA1]);
    GLDS(Bg0, &Bs[0][segB]);

    for (int k0 = 0; k0 < D_MODEL; k0 += 32) {
        const int cur = (k0 >> 5) & 1, nxt = cur ^ 1;
        __syncthreads();
        if (k0 + 32 < D_MODEL) {
            GLDS(Ag0 + k0 + 32, &As[nxt][segA0]);
            GLDS(Ag1 + k0 + 32, &As[nxt][segA1]);
            GLDS(Bg0 + k0 + 32, &Bs[nxt][segB]);
        }

        h16x8 af[4], bf[2];
#pragma unroll
        for (int mt = 0; mt < 4; mt++)
            af[mt] = *(const h16x8*)&As[cur][(wm + mt * 16 + l16) * 32 + fcol];
#pragma unroll
        for (int nt = 0; nt < 2; nt++)
            bf[nt] = *(const h16x8*)&Bs[cur][(wn + nt * 16 + l16) * 32 + fcol];
#pragma unroll
        for (int mt = 0; mt < 4; mt++)
#pragma unroll
            for (int nt = 0; nt < 2; nt++)
                acc[mt][nt] = MFMAH(af[mt], bf[nt], acc[mt][nt]);
    }

#pragma unroll
    for (int mt = 0; mt < 4; mt++)
#pragma unroll
        for (int nt = 0; nt < 2; nt++) {
            const int row = rowBase + wm + mt * 16 + quad * 4;
            const int col = colBase + wn + nt * 16 + l16;
#pragma unroll
            for (int r = 0; r < 4; r++)
                C[(size_t)(row + r) * D_MODEL + col] = acc[mt][nt][r];
        }
}

// ---------------------------------------------------------------------------
extern "C" void kernel_launch(void* const* d_in, const int* in_sizes, int n_in,
                              void* d_out, int out_size, void* d_ws, size_t ws_size,
                              hipStream_t stream)
{
    const float* x    = (const float*)d_in[0];
    const float* cosp = (const float*)d_in[1];
    const float* sinp = (const float*)d_in[2];
    const float* Wq   = (const float*)d_in[3];
    const float* Wk   = (const float*)d_in[4];
    const float* Wv   = (const float*)d_in[5];
    const float* Wo   = (const float*)d_in[6];

    char* w = (char*)d_ws;
    ushort_t* xb     = (ushort_t*)w;                       w += (size_t)MROWS * D_MODEL * 2;
    ushort_t* WqkvT  = (ushort_t*)w;                       w += (size_t)QKVN * D_MODEL * 2;
    ushort_t* WoT    = (ushort_t*)w;                       w += (size_t)D_MODEL * D_MODEL * 2;
    ushort_t* QKVh   = (ushort_t*)w;                       w += (size_t)MROWS * QKVN * 2;
    ushort_t* Kbuf   = (ushort_t*)w;                       w += (size_t)MROWS * KVDIM * 2;
    ushort_t* Vt     = (ushort_t*)w;                       w += (size_t)MROWS * KVDIM * 2;
    ushort_t* Obuf   = (ushort_t*)w;                       w += (size_t)MROWS * D_MODEL * 2;
    ushort_t* Pnum   = (ushort_t*)w;                       w += (size_t)NSPLIT * NTASK * 64 * 2;
    float*    Pl     = (float*)w;

    // --- fused prep (cast + 4 transposes): 1 dispatch
    prep_kernel<<<6656, 256, 0, stream>>>(x, Wq, Wk, Wv, Wo, xb, WqkvT, WoT);

    // --- fused QKV projection (f16 out), 128x64 tile
    gemm_qkv<<<dim3(QKVN / 64, MROWS / 128), 256, 0, stream>>>(
        xb, WqkvT, QKVh, MROWS, QKVN, D_MODEL);

    // --- fused K-rope + V transpose: 1 dispatch (Q-rope fused into attn)
    ropevt_kernel<<<NKBLK + 1024, 256, 0, stream>>>(
        QKVh, cosp, sinp, Kbuf, Vt);

    // --- attention (split-K x2, in-register PV, KVBLK=128, fused Q-rope)
    attn_mfma<<<dim3(NN / 256, NHEADS, BB * NSPLIT), 256, 0, stream>>>(
        QKVh, cosp, sinp, Kbuf, Vt, Pnum, Pl);

    // --- 2-way split-K combine -> plain f16 matrix
    combine_kernel<<<(MROWS * D_MODEL / 8) / 256, 256, 0, stream>>>(
        Pnum, Pl, Obuf);

    // --- output projection (plain GEMM, fp32 out), 128x64 tile
    gemm_wo<<<dim3(D_MODEL / 64, MROWS / 128), 256, 0, stream>>>(
        Obuf, WoT, (float*)d_out);
}

// Round 13
// 184.960 us; speedup vs baseline: 1.0750x; 1.0311x over previous
//
#include <hip/hip_runtime.h>
#include <math.h>

#define D_MODEL 1024
#define NHEADS  16
#define NKV     4
#define HDIM    64
#define KVDIM   256
#define BB      2
#define NN      2048
#define MROWS   (BB*NN)        // 4096
#define QKVN    1536           // 1024 + 256 + 256
#define NTASK   (MROWS*NHEADS) // 65536
#define NSPLIT  2
#define KVBLK   128
#define NTILE   ((NN/NSPLIT)/KVBLK)   // 8

typedef unsigned short ushort_t;
typedef unsigned int uint_t;
typedef float    f32x4 __attribute__((ext_vector_type(4)));
typedef _Float16 h16x8 __attribute__((ext_vector_type(8)));
typedef _Float16 h16x4 __attribute__((ext_vector_type(4)));
typedef __fp16   fp16x2 __attribute__((ext_vector_type(2)));

#define MFMAH(A,B,C)  __builtin_amdgcn_mfma_f32_16x16x32_f16((A),(B),(C),0,0,0)
// NOTE spelling: carried-forward GCN-era intrinsic has NO underscore before f16
#define MFMA16(A,B,C) __builtin_amdgcn_mfma_f32_16x16x16f16((A),(B),(C),0,0,0)
// raw v_exp_f32 (1 instr) -- libm exp2f carries a ~6-instr denormal fixup
#define EXP2(x) __builtin_amdgcn_exp2f(x)

// async global->LDS, 16B per lane; LDS dest = wave-uniform base + lane*16
#define GLDS(gp, lp) __builtin_amdgcn_global_load_lds( \
    (const __attribute__((address_space(1))) void*)(gp), \
    (__attribute__((address_space(3))) void*)(lp), 16, 0, 0)

__device__ __forceinline__ ushort_t f2h(float f) {
    _Float16 h = (_Float16)f;
    return *(ushort_t*)&h;
}
__device__ __forceinline__ float h2f(ushort_t u) {
    return (float)(*(const _Float16*)&u);
}
// two fp32 -> packed f16x2, single v_cvt_pkrtz_f16_f32
__device__ __forceinline__ uint_t pk2h(float a, float b) {
    fp16x2 v = __builtin_amdgcn_cvt_pkrtz(a, b);
    return *(uint_t*)&v;
}

// ---------------------------------------------------------------------------
// Fused prep: cast x->f16 (blocks [0,4096)) + 4 weight transpose-casts
// (blocks [4096,6656)). One dispatch instead of five.
// ---------------------------------------------------------------------------
__global__ __launch_bounds__(256)
void prep_kernel(const float* __restrict__ x, const float* __restrict__ Wq,
                 const float* __restrict__ Wk, const float* __restrict__ Wv,
                 const float* __restrict__ Wo, ushort_t* __restrict__ xb,
                 ushort_t* __restrict__ WqkvT, ushort_t* __restrict__ WoT)
{
    __shared__ float T[32][33];
    int blk = blockIdx.x;
    if (blk < 4096) {                      // cast: 4096*256*4 = 4M elements
        const int i = blk * 256 + threadIdx.x;
        float4 v = ((const float4*)x)[i];
        uint2 o;
        o.x = pk2h(v.x, v.y);
        o.y = pk2h(v.z, v.w);
        ((uint2*)xb)[i] = o;
        return;
    }
    blk -= 4096;
    const float* src; ushort_t* dst; int N, bx, by;
    if (blk < 1024)      { src = Wq; dst = WqkvT;                            N = D_MODEL; bx = blk & 31; by = blk >> 5; }
    else if (blk < 1280) { blk -= 1024; src = Wk; dst = WqkvT + (size_t)1024 * D_MODEL; N = KVDIM; bx = blk & 7; by = blk >> 3; }
    else if (blk < 1536) { blk -= 1280; src = Wv; dst = WqkvT + (size_t)1280 * D_MODEL; N = KVDIM; bx = blk & 7; by = blk >> 3; }
    else                 { blk -= 1536; src = Wo; dst = WoT;                 N = D_MODEL; bx = blk & 31; by = blk >> 5; }
    const int tx = threadIdx.x & 31, ty = threadIdx.x >> 5;
    const int n0 = bx * 32, k0 = by * 32;
#pragma unroll
    for (int i = 0; i < 4; i++)
        T[ty + i * 8][tx] = src[(size_t)(k0 + ty + i * 8) * N + n0 + tx];
    __syncthreads();
#pragma unroll
    for (int i = 0; i < 4; i++)
        dst[(size_t)(n0 + ty + i * 8) * D_MODEL + k0 + tx] = f2h(T[tx][ty + i * 8]);
}

// ---------------------------------------------------------------------------
// Fused K-RoPE + V transpose (Q-rope lives in attn). One dispatch.
// Blocks [0, NKBLK): K rope; blocks [NKBLK, +1024): vtrans.
// ---------------------------------------------------------------------------
#define NKW (MROWS*NKV*32)      //   524,288
#define NKBLK (NKW / 256)       //   2048
__global__ __launch_bounds__(256)
void ropevt_kernel(const ushort_t* __restrict__ QKVh, const float* __restrict__ Cos,
                   const float* __restrict__ Sin, ushort_t* __restrict__ Kb,
                   ushort_t* __restrict__ Vt)
{
    __shared__ ushort_t T[32][34];
    if (blockIdx.x >= NKBLK) {
        const int blk2 = blockIdx.x - NKBLK;
        const int bx = blk2 & 63, by = (blk2 >> 6) & 7, b = blk2 >> 9;
        const int tx = threadIdx.x & 31, ty = threadIdx.x >> 5;
        const int n0 = bx * 32, d0 = by * 32;
#pragma unroll
        for (int i = 0; i < 4; i++)
            T[ty + i * 8][tx] =
                QKVh[(size_t)(b * NN + n0 + ty + i * 8) * QKVN + 1280 + d0 + tx];
        __syncthreads();
#pragma unroll
        for (int i = 0; i < 4; i++)
            Vt[(size_t)(b * 256 + d0 + ty + i * 8) * NN + n0 + tx] = T[tx][ty + i * 8];
        return;
    }
    const int i2 = blockIdx.x * 256 + threadIdx.x;
    const int row = i2 >> 7, rem = i2 & 127;
    const int h = rem >> 5, j = rem & 31;
    const int b = row >> 11, n = row & (NN - 1);
    const uint_t pr = *(const uint_t*)&QKVh[(size_t)row * QKVN + 1024 + h * 64 + 2 * j];
    const float e = h2f((ushort_t)pr), o = h2f((ushort_t)(pr >> 16));
    const float c = Cos[n * 32 + j], s = Sin[n * 32 + j];
    ushort_t* dst = Kb + ((size_t)(b * 4 + h) * NN + n) * 64;
    dst[j]      = f2h(e * c - o * s);
    dst[j + 32] = f2h(e * s + o * c);
}

// ---------------------------------------------------------------------------
// f16 MFMA GEMM (f16 out), 128x64 tile. Round-25: 4-slot LDS ring, ONE
// barrier per K-pair (64 K) instead of per 32-K step -- halves the
// vmcnt(0)+lgkm drain count (the known ~20% stall of this structure).
// Staging/swizzle/fragment math byte-identical to the proven r8 template;
// only buffer indexing changed. LDS 48KB: grid 768 -> 3 blocks/CU, LDS
// allows exactly 3 (no occupancy loss).
// ---------------------------------------------------------------------------
__global__ __launch_bounds__(256)
void gemm_qkv(const ushort_t* __restrict__ A, const ushort_t* __restrict__ Bt,
              ushort_t* __restrict__ C, int M, int N, int K)
{
    __shared__ ushort_t As[4][128 * 32];
    __shared__ ushort_t Bs[4][64 * 32];

    const int tid  = threadIdx.x;
    const int wave = tid >> 6, lane = tid & 63;
    const int quad = lane >> 4, l16 = lane & 15;
    const int rowBase = blockIdx.y * 128, colBase = blockIdx.x * 64;
    const int wm = (wave >> 1) * 64, wn = (wave & 1) * 32;

    f32x4 acc[4][2];
    const f32x4 zz = {0.f, 0.f, 0.f, 0.f};
#pragma unroll
    for (int i = 0; i < 4; i++)
#pragma unroll
        for (int j = 0; j < 2; j++) acc[i][j] = zz;

    const int sr = wave * 32 + (lane >> 2);
    const int sc = ((lane & 3) ^ ((lane >> 3) & 3)) * 8;
    const ushort_t* Ag0 = A + (size_t)(rowBase + sr) * K + sc;
    const ushort_t* Ag1 = A + (size_t)(rowBase + sr + 16) * K + sc;
    const int segA0 = (wave * 2 + 0) * 512, segA1 = (wave * 2 + 1) * 512;
    const int br = wave * 16 + (lane >> 2);
    const ushort_t* Bg0 = Bt + (size_t)(colBase + br) * K + sc;
    const int segB = wave * 512;

    const int fcol = (quad ^ ((l16 >> 1) & 3)) * 8;

    // prologue: stage slots 0 (k=0) and 1 (k=32)
    GLDS(Ag0, &As[0][segA0]);
    GLDS(Ag1, &As[0][segA1]);
    GLDS(Bg0, &Bs[0][segB]);
    GLDS(Ag0 + 32, &As[1][segA0]);
    GLDS(Ag1 + 32, &As[1][segA1]);
    GLDS(Bg0 + 32, &Bs[1][segB]);

#define QKV_COMPUTE(curslot, koff) { \
        h16x8 af[4], bf[2]; \
        _Pragma("unroll") \
        for (int mt = 0; mt < 4; mt++) \
            af[mt] = *(const h16x8*)&As[curslot][(wm + mt * 16 + l16) * 32 + fcol]; \
        _Pragma("unroll") \
        for (int nt = 0; nt < 2; nt++) \
            bf[nt] = *(const h16x8*)&Bs[curslot][(wn + nt * 16 + l16) * 32 + fcol]; \
        _Pragma("unroll") \
        for (int mt = 0; mt < 4; mt++) \
            _Pragma("unroll") \
            for (int nt = 0; nt < 2; nt++) \
                acc[mt][nt] = MFMAH(af[mt], bf[nt], acc[mt][nt]); \
    }

    for (int k0 = 0; k0 < K; k0 += 64) {
        const int s0 = (k0 >> 5) & 3, s1 = (s0 + 1) & 3;
        const int s2 = (s0 + 2) & 3, s3 = (s0 + 3) & 3;
        __syncthreads();   // slots s0,s1 staged (issued last pair) now drained
        if (k0 + 64 < K) {
            GLDS(Ag0 + k0 + 64, &As[s2][segA0]);
            GLDS(Ag1 + k0 + 64, &As[s2][segA1]);
            GLDS(Bg0 + k0 + 64, &Bs[s2][segB]);
        }
        if (k0 + 96 < K) {
            GLDS(Ag0 + k0 + 96, &As[s3][segA0]);
            GLDS(Ag1 + k0 + 96, &As[s3][segA1]);
            GLDS(Bg0 + k0 + 96, &Bs[s3][segB]);
        }
        QKV_COMPUTE(s0, k0);
        QKV_COMPUTE(s1, k0 + 32);
    }
#undef QKV_COMPUTE

#pragma unroll
    for (int mt = 0; mt < 4; mt++)
#pragma unroll
        for (int nt = 0; nt < 2; nt++) {
            const int row = rowBase + wm + mt * 16 + quad * 4;
            const int col = colBase + wn + nt * 16 + l16;
#pragma unroll
            for (int r = 0; r < 4; r++)
                C[(size_t)(row + r) * N + col] = f2h(acc[mt][nt][r]);
        }
}

// ---------------------------------------------------------------------------
// MFMA flash attention (round-12 structure, UNCHANGED): NSPLIT=2, fused
// Q-rope, in-register K=16 PV, raw v_exp, KVBLK=128, MFMA denominator,
// 2 barriers/tile.
// ---------------------------------------------------------------------------
__global__ __launch_bounds__(256)
void attn_mfma(const ushort_t* __restrict__ QKVh, const float* __restrict__ Cos,
               const float* __restrict__ Sin, const ushort_t* __restrict__ Kb,
               const ushort_t* __restrict__ Vt, ushort_t* __restrict__ Pnum,
               float* __restrict__ Pl)
{
    const int qt = blockIdx.x, h = blockIdx.y;
    const int b = blockIdx.z >> 1, chunk = blockIdx.z & 1;
    const int kvh = h >> 2;
    const int tid = threadIdx.x;
    const int wave = tid >> 6, lane = tid & 63;
    const int quad = lane >> 4, l16 = lane & 15;

    __shared__ ushort_t Ks[128][72];
    __shared__ ushort_t Vs[64][136];

    const int row0 = qt * 256 + wave * 64;
    const float SC = 0.125f * 1.44269504f;

    h16x8 qf[4][2];
#pragma unroll
    for (int mt = 0; mt < 4; mt++) {
        const int n = row0 + mt * 16 + l16;
        // pre-rope Q row: cols h*64 + [2j, 2j+1] for j = quad*8 + i
        const uint_t* pr =
            (const uint_t*)(QKVh + (size_t)(b * NN + n) * QKVN + h * 64) + quad * 8;
        uint4 pa = *(const uint4*)pr;
        uint4 pc = *(const uint4*)(pr + 4);
        const uint_t pk[8] = {pa.x, pa.y, pa.z, pa.w, pc.x, pc.y, pc.z, pc.w};
        const float4 c0 = *(const float4*)&Cos[(size_t)n * 32 + quad * 8];
        const float4 c1 = *(const float4*)&Cos[(size_t)n * 32 + quad * 8 + 4];
        const float4 s0 = *(const float4*)&Sin[(size_t)n * 32 + quad * 8];
        const float4 s1 = *(const float4*)&Sin[(size_t)n * 32 + quad * 8 + 4];
        const float cc[8] = {c0.x, c0.y, c0.z, c0.w, c1.x, c1.y, c1.z, c1.w};
        const float ss[8] = {s0.x, s0.y, s0.z, s0.w, s1.x, s1.y, s1.z, s1.w};
#pragma unroll
        for (int i = 0; i < 8; i++) {
            const float e = h2f((ushort_t)pk[i]);
            const float o = h2f((ushort_t)(pk[i] >> 16));
            qf[mt][0][i] = (_Float16)((e * cc[i] - o * ss[i]) * SC);
            qf[mt][1][i] = (_Float16)((e * ss[i] + o * cc[i]) * SC);
        }
    }

    h16x4 ones;
#pragma unroll
    for (int i = 0; i < 4; i++) ones[i] = (_Float16)1.0f;

    const ushort_t* kbase = Kb + (size_t)(b * 4 + kvh) * NN * 64;
    const ushort_t* vbase = Vt + (size_t)(b * 256 + kvh * 64) * NN;
    const int key_lo = chunk * (NN / NSPLIT);          // 1024-key chunk
    const int rot = (qt + ((h & 3) << 2)) & (NTILE - 1);

    const int srow = tid >> 2, sseg = (tid & 3) * 8;
    const ushort_t* kp_lane = kbase + (size_t)srow * 64 + sseg;   // + key*64
    const ushort_t* vp_lane = vbase + (size_t)srow * NN + sseg;   // + key

    const f32x4 zz = {0.f, 0.f, 0.f, 0.f};
    f32x4 o[4][4];
#pragma unroll
    for (int mt = 0; mt < 4; mt++)
#pragma unroll
        for (int dt = 0; dt < 4; dt++) o[mt][dt] = zz;
    f32x4 lsum[4];
#pragma unroll
    for (int mt = 0; mt < 4; mt++) lsum[mt] = zz;

    const int key0 = key_lo + rot * KVBLK;
    uint4 kreg0 = *(const uint4*)(kp_lane + (size_t)key0 * 64);
    uint4 kreg1 = *(const uint4*)(kp_lane + (size_t)key0 * 64 + 32);
    uint4 kreg2 = *(const uint4*)(kp_lane + (size_t)(key0 + 64) * 64);
    uint4 kreg3 = *(const uint4*)(kp_lane + (size_t)(key0 + 64) * 64 + 32);
    uint4 vreg0 = *(const uint4*)(vp_lane + key0);
    uint4 vreg1 = *(const uint4*)(vp_lane + key0 + 32);
    uint4 vreg2 = *(const uint4*)(vp_lane + key0 + 64);
    uint4 vreg3 = *(const uint4*)(vp_lane + key0 + 96);

    for (int t = 0; t < NTILE; t++) {
        __syncthreads();
        *(uint4*)&Ks[srow][sseg]           = kreg0;
        *(uint4*)&Ks[srow][sseg + 32]      = kreg1;
        *(uint4*)&Ks[srow + 64][sseg]      = kreg2;
        *(uint4*)&Ks[srow + 64][sseg + 32] = kreg3;
        *(uint4*)&Vs[srow][sseg]           = vreg0;
        *(uint4*)&Vs[srow][sseg + 32]      = vreg1;
        *(uint4*)&Vs[srow][sseg + 64]      = vreg2;
        *(uint4*)&Vs[srow][sseg + 96]      = vreg3;
        __syncthreads();

        if (t < NTILE - 1) {
            const int kn = key_lo + ((rot + t + 1) & (NTILE - 1)) * KVBLK;
            kreg0 = *(const uint4*)(kp_lane + (size_t)kn * 64);
            kreg1 = *(const uint4*)(kp_lane + (size_t)kn * 64 + 32);
            kreg2 = *(const uint4*)(kp_lane + (size_t)(kn + 64) * 64);
            kreg3 = *(const uint4*)(kp_lane + (size_t)(kn + 64) * 64 + 32);
            vreg0 = *(const uint4*)(vp_lane + kn);
            vreg1 = *(const uint4*)(vp_lane + kn + 32);
            vreg2 = *(const uint4*)(vp_lane + kn + 64);
            vreg3 = *(const uint4*)(vp_lane + kn + 96);
        }

        // ---- fused per-kt: S^T = K Q^T -> exp2 -> pack -> PV (K=16, P in regs)
#pragma unroll
        for (int kt = 0; kt < 8; kt++) {
            h16x8 kf0 = *(const h16x8*)&Ks[kt * 16 + l16][quad * 8];
            h16x8 kf1 = *(const h16x8*)&Ks[kt * 16 + l16][32 + quad * 8];
            // V fragments for this kt: A-layout (K=16) = Vt[d][kt*16+quad*4+i]
            h16x4 va[4];
#pragma unroll
            for (int dt = 0; dt < 4; dt++)
                va[dt] = *(const h16x4*)&Vs[dt * 16 + l16][kt * 16 + quad * 4];

            uint2 pb[4];
#pragma unroll
            for (int mt = 0; mt < 4; mt++) {
                f32x4 st = MFMAH(kf0, qf[mt][0], zz);
                st = MFMAH(kf1, qf[mt][1], st);
                pb[mt].x = pk2h(EXP2(st[0]), EXP2(st[1]));
                pb[mt].y = pk2h(EXP2(st[2]), EXP2(st[3]));
            }
#pragma unroll
            for (int mt = 0; mt < 4; mt++) {
                const h16x4 pbv = *(const h16x4*)&pb[mt];
#pragma unroll
                for (int dt = 0; dt < 4; dt++)
                    o[mt][dt] = MFMA16(va[dt], pbv, o[mt][dt]);
                lsum[mt] = MFMA16(ones, pbv, lsum[mt]);
            }
        }
    }

    const size_t task0 = (size_t)(b * 16 + h) * NN + row0;
    ushort_t* np = Pnum + ((size_t)chunk * NTASK + task0) * 64;
#pragma unroll
    for (int mt = 0; mt < 4; mt++) {
        const float lt = lsum[mt][0];    // denom for q=l16 (rows identical)
        const float inv = 1.0f / lt;
#pragma unroll
        for (int dt = 0; dt < 4; dt++) {
            f32x4 v = o[mt][dt];
            uint2 pk;
            pk.x = pk2h(v[0] * inv, v[1] * inv);
            pk.y = pk2h(v[2] * inv, v[3] * inv);
            *(uint2*)&np[(size_t)(mt * 16 + l16) * 64 + dt * 16 + quad * 4] = pk;
        }
        if (quad == 0)
            Pl[(size_t)chunk * NTASK + task0 + mt * 16 + l16] = lt;
    }
}

// ---------------------------------------------------------------------------
// Split-K combine (2-way) + relayout to plain [row][D_MODEL] f16 matrix.
// ---------------------------------------------------------------------------
__global__ __launch_bounds__(256)
void combine_kernel(const ushort_t* __restrict__ Pnum, const float* __restrict__ Pl,
                    ushort_t* __restrict__ Ob)
{
    const uint_t i = blockIdx.x * 256 + threadIdx.x;   // 8-elem group, 524288 total
    const int row = i >> 7;            // 128 groups per 1024-col row
    const int g = i & 127;
    const int col0 = g * 8;
    const int h = col0 >> 6, d = col0 & 63;
    const int b = row >> 11, n = row & (NN - 1);
    const size_t task = ((size_t)(b * 16 + h) << 11) + n;

    float l[NSPLIT], tot = 0.f;
#pragma unroll
    for (int c = 0; c < NSPLIT; c++) { l[c] = Pl[(size_t)c * NTASK + task]; tot += l[c]; }
    const float inv = 1.f / tot;

    uint4 in[NSPLIT];
#pragma unroll
    for (int c = 0; c < NSPLIT; c++)
        in[c] = *(const uint4*)&Pnum[((size_t)c * NTASK + task) * 64 + d];

    uint4 out;
    uint_t* po = (uint_t*)&out;
#pragma unroll
    for (int j = 0; j < 4; j++) {
        float x = 0.f, y = 0.f;
#pragma unroll
        for (int c = 0; c < NSPLIT; c++) {
            const float w = l[c] * inv;
            fp16x2 u = *(const fp16x2*)&((const uint_t*)&in[c])[j];
            x += w * (float)u.x;
            y += w * (float)u.y;
        }
        po[j] = pk2h(x, y);
    }
    *(uint4*)&Ob[(size_t)row * D_MODEL + col0] = out;
}

// ---------------------------------------------------------------------------
// Wo GEMM: plain f16 GEMM (fp32 out), 128x64 tile, 4-slot ring (one barrier
// per K-pair, same transformation as gemm_qkv).
// ---------------------------------------------------------------------------
__global__ __launch_bounds__(256)
void gemm_wo(const ushort_t* __restrict__ A, const ushort_t* __restrict__ Bt,
             float* __restrict__ C)
{
    __shared__ ushort_t As[4][128 * 32];
    __shared__ ushort_t Bs[4][64 * 32];

    const int tid  = threadIdx.x;
    const int wave = tid >> 6, lane = tid & 63;
    const int quad = lane >> 4, l16 = lane & 15;
    const int rowBase = blockIdx.y * 128, colBase = blockIdx.x * 64;
    const int wm = (wave >> 1) * 64, wn = (wave & 1) * 32;

    f32x4 acc[4][2];
    const f32x4 zz = {0.f, 0.f, 0.f, 0.f};
#pragma unroll
    for (int i = 0; i < 4; i++)
#pragma unroll
        for (int j = 0; j < 2; j++) acc[i][j] = zz;

    const int sr = wave * 32 + (lane >> 2);
    const int sc = ((lane & 3) ^ ((lane >> 3) & 3)) * 8;
    const ushort_t* Ag0 = A + (size_t)(rowBase + sr) * D_MODEL + sc;
    const ushort_t* Ag1 = A + (size_t)(rowBase + sr + 16) * D_MODEL + sc;
    const int segA0 = (wave * 2 + 0) * 512, segA1 = (wave * 2 + 1) * 512;
    const int br = wave * 16 + (lane >> 2);
    const ushort_t* Bg0 = Bt + (size_t)(colBase + br) * D_MODEL + sc;
    const int segB = wave * 512;

    const int fcol = (quad ^ ((l16 >> 1) & 3)) * 8;

    GLDS(Ag0, &As[0][segA0]);
    GLDS(Ag1, &As[0][segA1]);
    GLDS(Bg0, &Bs[0][segB]);
    GLDS(Ag0 + 32, &As[1][segA0]);
    GLDS(Ag1 + 32, &As[1][segA1]);
    GLDS(Bg0 + 32, &Bs[1][segB]);

#define WO_COMPUTE(curslot) { \
        h16x8 af[4], bf[2]; \
        _Pragma("unroll") \
        for (int mt = 0; mt < 4; mt++) \
            af[mt] = *(const h16x8*)&As[curslot][(wm + mt * 16 + l16) * 32 + fcol]; \
        _Pragma("unroll") \
        for (int nt = 0; nt < 2; nt++) \
            bf[nt] = *(const h16x8*)&Bs[curslot][(wn + nt * 16 + l16) * 32 + fcol]; \
        _Pragma("unroll") \
        for (int mt = 0; mt < 4; mt++) \
            _Pragma("unroll") \
            for (int nt = 0; nt < 2; nt++) \
                acc[mt][nt] = MFMAH(af[mt], bf[nt], acc[mt][nt]); \
    }

    for (int k0 = 0; k0 < D_MODEL; k0 += 64) {
        const int s0 = (k0 >> 5) & 3, s1 = (s0 + 1) & 3;
        const int s2 = (s0 + 2) & 3, s3 = (s0 + 3) & 3;
        __syncthreads();
        if (k0 + 64 < D_MODEL) {
            GLDS(Ag0 + k0 + 64, &As[s2][segA0]);
            GLDS(Ag1 + k0 + 64, &As[s2][segA1]);
            GLDS(Bg0 + k0 + 64, &Bs[s2][segB]);
        }
        if (k0 + 96 < D_MODEL) {
            GLDS(Ag0 + k0 + 96, &As[s3][segA0]);
            GLDS(Ag1 + k0 + 96, &As[s3][segA1]);
            GLDS(Bg0 + k0 + 96, &Bs[s3][segB]);
        }
        WO_COMPUTE(s0);
        WO_COMPUTE(s1);
    }
#undef WO_COMPUTE

#pragma unroll
    for (int mt = 0; mt < 4; mt++)
#pragma unroll
        for (int nt = 0; nt < 2; nt++) {
            const int row = rowBase + wm + mt * 16 + quad * 4;
            const int col = colBase + wn + nt * 16 + l16;
#pragma unroll
            for (int r = 0; r < 4; r++)
                C[(size_t)(row + r) * D_MODEL + col] = acc[mt][nt][r];
        }
}

// ---------------------------------------------------------------------------
extern "C" void kernel_launch(void* const* d_in, const int* in_sizes, int n_in,
                              void* d_out, int out_size, void* d_ws, size_t ws_size,
                              hipStream_t stream)
{
    const float* x    = (const float*)d_in[0];
    const float* cosp = (const float*)d_in[1];
    const float* sinp = (const float*)d_in[2];
    const float* Wq   = (const float*)d_in[3];
    const float* Wk   = (const float*)d_in[4];
    const float* Wv   = (const float*)d_in[5];
    const float* Wo   = (const float*)d_in[6];

    char* w = (char*)d_ws;
    ushort_t* xb     = (ushort_t*)w;                       w += (size_t)MROWS * D_MODEL * 2;
    ushort_t* WqkvT  = (ushort_t*)w;                       w += (size_t)QKVN * D_MODEL * 2;
    ushort_t* WoT    = (ushort_t*)w;                       w += (size_t)D_MODEL * D_MODEL * 2;
    ushort_t* QKVh   = (ushort_t*)w;                       w += (size_t)MROWS * QKVN * 2;
    ushort_t* Kbuf   = (ushort_t*)w;                       w += (size_t)MROWS * KVDIM * 2;
    ushort_t* Vt     = (ushort_t*)w;                       w += (size_t)MROWS * KVDIM * 2;
    ushort_t* Obuf   = (ushort_t*)w;                       w += (size_t)MROWS * D_MODEL * 2;
    ushort_t* Pnum   = (ushort_t*)w;                       w += (size_t)NSPLIT * NTASK * 64 * 2;
    float*    Pl     = (float*)w;

    // --- fused prep (cast + 4 transposes): 1 dispatch
    prep_kernel<<<6656, 256, 0, stream>>>(x, Wq, Wk, Wv, Wo, xb, WqkvT, WoT);

    // --- fused QKV projection (f16 out), 128x64 tile, 4-slot ring
    gemm_qkv<<<dim3(QKVN / 64, MROWS / 128), 256, 0, stream>>>(
        xb, WqkvT, QKVh, MROWS, QKVN, D_MODEL);

    // --- fused K-rope + V transpose: 1 dispatch (Q-rope fused into attn)
    ropevt_kernel<<<NKBLK + 1024, 256, 0, stream>>>(
        QKVh, cosp, sinp, Kbuf, Vt);

    // --- attention (split-K x2, in-register PV, KVBLK=128, fused Q-rope)
    attn_mfma<<<dim3(NN / 256, NHEADS, BB * NSPLIT), 256, 0, stream>>>(
        QKVh, cosp, sinp, Kbuf, Vt, Pnum, Pl);

    // --- 2-way split-K combine -> plain f16 matrix
    combine_kernel<<<(MROWS * D_MODEL / 8) / 256, 256, 0, stream>>>(
        Pnum, Pl, Obuf);

    // --- output projection (plain GEMM, fp32 out), 128x64 tile, 4-slot ring
    gemm_wo<<<dim3(D_MODEL / 64, MROWS / 128), 256, 0, stream>>>(
        Obuf, WoT, (float*)d_out);
}